// Round 10
// baseline (1310.354 us; speedup 1.0000x reference)
//
#include <hip/hip_runtime.h>
#include <hip/hip_bf16.h>

// ---------------------------------------------------------------------------
// Conv-TasNet TCN, bf16-MFMA v9.
// vs v8(raced): REVERT GEMM core to v7's proven single-buffer mm6 (2 barriers
// per K-step, no dbuf, no setprio). NEW: serial-trunk fusion rsp = rs_i +
// pw_{i+1}: res blocks hand their fresh bf16 OUT tile to stage 2 via a 16KB
// XOR-swizzled LDS tile and compute the next pw for their t-tile in the same
// kernel. Standard barriers only — deterministic by construction.
// ---------------------------------------------------------------------------

#define T_  4000
#define TP_ 4096
#define B_  4
#define YHAL 128
#define YROW 512
#define YSST ((size_t)(TP_ + 2 * YHAL) * YROW)
#define USST ((size_t)TP_ * YROW)
#define NSUB 64
#define SLOTW (NSUB * 8)

typedef __attribute__((ext_vector_type(8))) short  s8v;
typedef __attribute__((ext_vector_type(4))) float  f32x4;
typedef __attribute__((ext_vector_type(4))) unsigned short u16x4;

__device__ __forceinline__ float bf2f(unsigned short u) {
  unsigned int i = ((unsigned int)u) << 16;
  float f; __builtin_memcpy(&f, &i, 4); return f;
}
__device__ __forceinline__ unsigned short f2bf(float f) {
  unsigned int i; __builtin_memcpy(&i, &f, 4);
  unsigned int r = i + 0x7fffu + ((i >> 16) & 1u);
  return (unsigned short)(r >> 16);
}

__device__ __forceinline__ void g2lds16(const void* g, void* l) {
  __builtin_amdgcn_global_load_lds(
      (const __attribute__((address_space(1))) unsigned int*)g,
      (__attribute__((address_space(3))) unsigned int*)l, 16, 0, 0);
}

// consumer-side: sum the 64 sub-slot partials of one stats slot (per-wave).
__device__ __forceinline__ void stats_sum(const float* __restrict__ si, int b,
                                          float& u, float& q) {
  const int lane = threadIdx.x & 63;
  u = si[lane * 8 + b * 2 + 0];
  q = si[lane * 8 + b * 2 + 1];
#pragma unroll
  for (int off = 32; off > 0; off >>= 1) {
    u += __shfl_xor(u, off);
    q += __shfl_xor(q, off);
  }
}

// ---------------- per-sample sum/sumsq over contiguous [C*T] ---------------
__global__ __launch_bounds__(256) void gn_stats(const float* __restrict__ X,
                                                float* __restrict__ statsOut, int n) {
  const int b = blockIdx.y;
  const float4* xp = (const float4*)(X + (size_t)b * n);
  const int n4 = n >> 2;
  float s1 = 0.f, s2 = 0.f;
  for (int idx = blockIdx.x * 256 + threadIdx.x; idx < n4; idx += gridDim.x * 256) {
    float4 v = xp[idx];
    s1 += v.x + v.y + v.z + v.w;
    s2 += v.x * v.x + v.y * v.y + v.z * v.z + v.w * v.w;
  }
#pragma unroll
  for (int off = 32; off > 0; off >>= 1) {
    s1 += __shfl_xor(s1, off);
    s2 += __shfl_xor(s2, off);
  }
  __shared__ float red[8];
  const int lane = threadIdx.x & 63, wv = threadIdx.x >> 6;
  if (lane == 0) { red[wv] = s1; red[4 + wv] = s2; }
  __syncthreads();
  if (threadIdx.x == 0) {
    float* dst = statsOut + (size_t)(blockIdx.x & (NSUB - 1)) * 8 + b * 2;
    atomicAdd(&dst[0], red[0] + red[1] + red[2] + red[3]);
    atomicAdd(&dst[1], red[4] + red[5] + red[6] + red[7]);
  }
}

// ---------------- weight prep ----------------------------------------------
__global__ __launch_bounds__(256) void cvt_bf(const float* __restrict__ s,
                                              unsigned short* __restrict__ d, int n) {
  for (int i = blockIdx.x * 256 + threadIdx.x; i < n; i += gridDim.x * 256)
    d[i] = f2bf(s[i]);
}

__global__ __launch_bounds__(256) void fold_rs(
    const float* __restrict__ rw, const float* __restrict__ sw,
    const float* __restrict__ g2a, const float* __restrict__ b2a,
    unsigned short* __restrict__ Wg, float* __restrict__ Ucb,
    float* __restrict__ Vcb) {
  const int row = blockIdx.x;                 // i*256 + m
  const int i = row >> 8, m = row & 255;
  const float* src = (m < 128) ? rw + ((size_t)i * 128 + m) * 512
                               : sw + ((size_t)i * 128 + (m - 128)) * 512;
  const float* g = g2a + (size_t)i * 512;
  const float* bb = b2a + (size_t)i * 512;
  unsigned short* dst = Wg + (size_t)row * 512;
  float u = 0.f, v = 0.f;
  for (int h = threadIdx.x; h < 512; h += 256) {
    float wgt = src[h] * g[h];
    dst[h] = f2bf(wgt);
    u += wgt; v += src[h] * bb[h];
  }
#pragma unroll
  for (int off = 32; off > 0; off >>= 1) {
    u += __shfl_xor(u, off);
    v += __shfl_xor(v, off);
  }
  __shared__ float red[8];
  const int lane = threadIdx.x & 63, wv = threadIdx.x >> 6;
  if (lane == 0) { red[wv] = u; red[4 + wv] = v; }
  __syncthreads();
  if (threadIdx.x == 0) {
    Ucb[row] = red[0] + red[1] + red[2] + red[3];
    Vcb[row] = red[4] + red[5] + red[6] + red[7];
  }
}

// both heads' prelu+cvt in one launch
__global__ __launch_bounds__(256) void prelu2(const float* __restrict__ S0,
                                              const float* __restrict__ S1,
                                              unsigned short* __restrict__ D,
                                              const float* __restrict__ a0p,
                                              const float* __restrict__ a1p, int n) {
  const float a0 = a0p[0], a1 = a1p[0];
  for (int i = blockIdx.x * 256 + threadIdx.x; i < 2 * n; i += gridDim.x * 256) {
    float v = (i < n) ? S0[i] : S1[i - n];
    float a = (i < n) ? a0 : a1;
    v = v >= 0.f ? v : a * v;
    D[i] = f2bf(v);
  }
}

// ---------------- input transpose + GN affine + bf16 -----------------------
__global__ __launch_bounds__(256) void tin(const float* __restrict__ X,
                                           unsigned short* __restrict__ Xt,
                                           const float* __restrict__ g,
                                           const float* __restrict__ bt,
                                           const float* __restrict__ sIn, float invN) {
  const int b = blockIdx.z, c0 = blockIdx.y * 64, t0 = blockIdx.x * 64;
  __shared__ float tile[64][65];
  const int tid = threadIdx.x;
  float su, sq;
  stats_sum(sIn, b, su, sq);
  const float mean = su * invN;
  const float rs = rsqrtf(sq * invN - mean * mean + 1e-8f);
  {
    const int cl = tid >> 2, tq = (tid & 3) * 16;
    const float* Xr = X + ((size_t)b * 256 + c0 + cl) * T_;
#pragma unroll
    for (int j = 0; j < 4; ++j) {
      int tt = t0 + tq + j * 4;
      float4 v;
      if (tt + 3 < T_) v = *(const float4*)(Xr + tt);
      else {
        v.x = (tt + 0 < T_) ? Xr[tt + 0] : 0.f;
        v.y = (tt + 1 < T_) ? Xr[tt + 1] : 0.f;
        v.z = (tt + 2 < T_) ? Xr[tt + 2] : 0.f;
        v.w = (tt + 3 < T_) ? Xr[tt + 3] : 0.f;
      }
      tile[cl][tq + j * 4 + 0] = v.x; tile[cl][tq + j * 4 + 1] = v.y;
      tile[cl][tq + j * 4 + 2] = v.z; tile[cl][tq + j * 4 + 3] = v.w;
    }
  }
  __syncthreads();
  {
    const int tl = tid >> 2, cq = (tid & 3) * 16;
    const int t = t0 + tl;
    if (t < T_) {
      unsigned short* dst = Xt + ((size_t)b * TP_ + t) * 256 + c0 + cq;
      s8v u0, u1;
#pragma unroll
      for (int j = 0; j < 16; ++j) {
        int c = c0 + cq + j;
        float sc = rs * g[c];
        float oc = bt[c] - mean * sc;
        unsigned short uu = f2bf(tile[cq + j][tl] * sc + oc);
        if (j < 8) u0[j] = (short)uu; else u1[j - 8] = (short)uu;
      }
      *(s8v*)dst = u0;
      *(s8v*)(dst + 8) = u1;
    }
  }
}

// ---------------- mm6 params ------------------------------------------------
struct MMP {
  const unsigned short *A0, *A1, *B0, *B1;
  const float *bias0, *bias1;
  float *O0a, *O0b, *O1a, *O1b;
  unsigned short *Obf0, *Obf1;
  const float *al0, *al1;
  float *so0, *so1;
  const float *si0, *si1;
  const float *Uc0, *Uc1, *Vc0, *Vc1, *rb0, *rb1, *sb0, *sb1;
  float* feat;
  float* dupO0; unsigned short* dupObf; float* dupO1;
  int K; float invN;
};

// ---------------- clean bf16 MFMA GEMM, 128m x TNt x 64k, single-buffer ----
// EPI 0: O0 fp32 [t][128] = v+bias, Obf shadow                (bn1)
// EPI 1: prelu -> Obf bf16 Y-slot (halo stride YSST) + GN stats (pw)
// EPI 2: GN2-folded; y==0: res RMW O0 + shadow; y==1: skip RMW O1
//        WF: also write feat [128][4000]; DUP: also write fork copies
// EPI 3: masked fp32 scatter O0[b][256][4000] = v+bias         (heads)
// FLG: 1=PAIR (blockIdx.z >= gridDim.z/2 -> branch-2 pointers)
template <int EPI, int TN, int FLG>
__global__ __launch_bounds__(256) void mm6(MMP p) {
  constexpr bool PAIR = (FLG & 1) != 0;
  constexpr bool WF   = (FLG & 2) != 0;
  constexpr bool DUPF = (FLG & 4) != 0;
  constexpr int NJ = TN / 32;
  __shared__ unsigned short As[128 * 64];
  __shared__ unsigned short Bs[TN * 64];
  __shared__ float redw[8];
  int b = blockIdx.z; bool br2 = false;
  if constexpr (PAIR) {
    const int h = gridDim.z >> 1;
    if (b >= h) { br2 = true; b -= h; }
  }
  const int K = p.K;
  const unsigned short* A  = br2 ? p.A1 : p.A0;
  const unsigned short* Bm = br2 ? p.B1 : p.B0;
  const int m0 = blockIdx.y * 128;
  const int t0 = blockIdx.x * TN;
  const int tid = threadIdx.x;
  const int lane = tid & 63;
  const int w = tid >> 6;
  const int wm = w >> 1, wn = w & 1;
  const int lt = lane & 15, lg = lane >> 4;
  const unsigned short* Ab = A + (size_t)m0 * K;
  const unsigned short* Bb = Bm + ((size_t)b * TP_ + t0) * K;
  const int srow8 = lane >> 3;
  const int skc   = ((lane & 7) ^ (lane >> 3)) * 8;

  f32x4 acc[4][NJ];
#pragma unroll
  for (int i = 0; i < 4; ++i)
#pragma unroll
    for (int j = 0; j < NJ; ++j) acc[i][j] = (f32x4){0.f, 0.f, 0.f, 0.f};

  for (int k0 = 0; k0 < K; k0 += 64) {
#pragma unroll
    for (int c = 0; c < 4; ++c) {
      const int ch = w * 4 + c;
      g2lds16(Ab + (size_t)(ch * 8 + srow8) * K + k0 + skc, &As[ch * 512]);
    }
#pragma unroll
    for (int c = 0; c < NJ; ++c) {
      const int ch = w * NJ + c;
      g2lds16(Bb + (size_t)(ch * 8 + srow8) * K + k0 + skc, &Bs[ch * 512]);
    }
    __syncthreads();
#pragma unroll
    for (int ks = 0; ks < 2; ++ks) {
      s8v bfr[NJ];
#pragma unroll
      for (int j = 0; j < NJ; ++j) {
        const int R = wn * (TN / 2) + j * 16 + lt;
        bfr[j] = *(const s8v*)&Bs[R * 64 + (((ks * 4 + lg) ^ (R & 7)) * 8)];
      }
#pragma unroll
      for (int i = 0; i < 4; ++i) {
        const int R = wm * 64 + i * 16 + lt;
        s8v af = *(const s8v*)&As[R * 64 + (((ks * 4 + lg) ^ (R & 7)) * 8)];
#pragma unroll
        for (int j = 0; j < NJ; ++j)
          acc[i][j] = __builtin_amdgcn_mfma_f32_16x16x32_bf16(af, bfr[j], acc[i][j], 0, 0, 0);
      }
    }
    __syncthreads();
  }

  // ---- epilogues. D row m = m0 + wm*64 + i*16 + lg*4 + r,
  //                 D col t = t0 + wn*(TN/2) + j*16 + lt
  if constexpr (EPI == 0) {
    const float* bias = p.bias0;
#pragma unroll
    for (int i = 0; i < 4; ++i) {
      const int mg = m0 + wm * 64 + i * 16 + lg * 4;
      float4 bi = *(const float4*)(bias + mg);
#pragma unroll
      for (int j = 0; j < NJ; ++j) {
        const int t = t0 + wn * (TN / 2) + j * 16 + lt;
        f32x4 v = acc[i][j];
        float nv[4] = {v[0] + bi.x, v[1] + bi.y, v[2] + bi.z, v[3] + bi.w};
        *(float4*)(p.O0a + ((size_t)b * TP_ + t) * 128 + mg) =
            make_float4(nv[0], nv[1], nv[2], nv[3]);
        u16x4 pk;
#pragma unroll
        for (int r = 0; r < 4; ++r) pk[r] = f2bf(nv[r]);
        *(u16x4*)(p.Obf0 + ((size_t)b * TP_ + t) * 128 + mg) = pk;
      }
    }
  } else if constexpr (EPI == 1) {
    const float* bias = br2 ? p.bias1 : p.bias0;
    unsigned short* Obf = (br2 ? p.Obf1 : p.Obf0) + (size_t)b * YSST;
    const float aO = (br2 ? p.al1 : p.al0)[0];
    float* so = br2 ? p.so1 : p.so0;
    float s1 = 0.f, s2 = 0.f;
#pragma unroll
    for (int i = 0; i < 4; ++i) {
      const int mg = m0 + wm * 64 + i * 16 + lg * 4;
      float4 bi = *(const float4*)(bias + mg);
      float bv[4] = {bi.x, bi.y, bi.z, bi.w};
#pragma unroll
      for (int j = 0; j < NJ; ++j) {
        const int t = t0 + wn * (TN / 2) + j * 16 + lt;
        f32x4 v = acc[i][j];
        u16x4 pk;
#pragma unroll
        for (int r = 0; r < 4; ++r) {
          float f = v[r] + bv[r];
          f = f >= 0.f ? f : aO * f;
          pk[r] = f2bf(f);
        }
        *(u16x4*)(Obf + (size_t)t * YROW + mg) = pk;
        if (t < T_) {
#pragma unroll
          for (int r = 0; r < 4; ++r) { float f = bf2f(pk[r]); s1 += f; s2 += f * f; }
        }
      }
    }
#pragma unroll
    for (int off = 32; off > 0; off >>= 1) {
      s1 += __shfl_xor(s1, off);
      s2 += __shfl_xor(s2, off);
    }
    if (lane == 0) { redw[w] = s1; redw[4 + w] = s2; }
    __syncthreads();
    if (tid == 0) {
      float* dst = so + (size_t)(blockIdx.x & (NSUB - 1)) * 8 + b * 2;
      atomicAdd(&dst[0], redw[0] + redw[1] + redw[2] + redw[3]);
      atomicAdd(&dst[1], redw[4] + redw[5] + redw[6] + redw[7]);
    }
  } else if constexpr (EPI == 2) {
    float* O0 = br2 ? p.O0b : p.O0a;
    float* O1 = br2 ? p.O1b : p.O1a;
    unsigned short* Obf = br2 ? p.Obf1 : p.Obf0;
    const float* si = br2 ? p.si1 : p.si0;
    const float* Uc = br2 ? p.Uc1 : p.Uc0;
    const float* Vc = br2 ? p.Vc1 : p.Vc0;
    const float* rb = br2 ? p.rb1 : p.rb0;
    const float* sb = br2 ? p.sb1 : p.sb0;
    float su, sq;
    stats_sum(si, b, su, sq);
    const float mean = su * p.invN;
    const float rsv = rsqrtf(sq * p.invN - mean * mean + 1e-8f);
    const bool isRes = (m0 == 0);
#pragma unroll
    for (int i = 0; i < 4; ++i) {
      const int ml = wm * 64 + i * 16 + lg * 4;   // 0..127 local
      float cc[4];
#pragma unroll
      for (int r = 0; r < 4; ++r) {
        const int mgG = m0 + ml + r;
        cc[r] = Vc[mgG] - mean * rsv * Uc[mgG] + (isRes ? rb[ml + r] : sb[ml + r]);
      }
#pragma unroll
      for (int j = 0; j < NJ; ++j) {
        const int t = t0 + wn * (TN / 2) + j * 16 + lt;
        f32x4 v = acc[i][j];
        if (isRes) {
          float* ptr = O0 + ((size_t)b * TP_ + t) * 128 + ml;
          float4 old = *(float4*)ptr;
          float nv[4] = {old.x + rsv * v[0] + cc[0], old.y + rsv * v[1] + cc[1],
                         old.z + rsv * v[2] + cc[2], old.w + rsv * v[3] + cc[3]};
          *(float4*)ptr = make_float4(nv[0], nv[1], nv[2], nv[3]);
          u16x4 pk;
#pragma unroll
          for (int r = 0; r < 4; ++r) pk[r] = f2bf(nv[r]);
          *(u16x4*)(Obf + ((size_t)b * TP_ + t) * 128 + ml) = pk;
          if constexpr (DUPF) {
            *(float4*)(p.dupO0 + ((size_t)b * TP_ + t) * 128 + ml) =
                make_float4(nv[0], nv[1], nv[2], nv[3]);
            *(u16x4*)(p.dupObf + ((size_t)b * TP_ + t) * 128 + ml) = pk;
          }
          if constexpr (WF) {
            if (t < T_) {
#pragma unroll
              for (int r = 0; r < 4; ++r)
                p.feat[((size_t)b * 128 + ml + r) * T_ + t] = nv[r];
            }
          }
        } else {
          float* ptr = O1 + ((size_t)b * TP_ + t) * 128 + ml;
          float4 old = *(float4*)ptr;
          float nv[4] = {old.x + rsv * v[0] + cc[0], old.y + rsv * v[1] + cc[1],
                         old.z + rsv * v[2] + cc[2], old.w + rsv * v[3] + cc[3]};
          *(float4*)ptr = make_float4(nv[0], nv[1], nv[2], nv[3]);
          if constexpr (DUPF) {
            *(float4*)(p.dupO1 + ((size_t)b * TP_ + t) * 128 + ml) =
                make_float4(nv[0], nv[1], nv[2], nv[3]);
          }
        }
      }
    }
  } else {  // EPI 3: heads scatter to [b][256][4000]
    float* O0 = br2 ? p.O0b : p.O0a;
    const float* bias = br2 ? p.bias1 : p.bias0;
#pragma unroll
    for (int i = 0; i < 4; ++i) {
      const int mg = m0 + wm * 64 + i * 16 + lg * 4;
#pragma unroll
      for (int j = 0; j < NJ; ++j) {
        const int t = t0 + wn * (TN / 2) + j * 16 + lt;
        if (t < T_) {
          f32x4 v = acc[i][j];
#pragma unroll
          for (int r = 0; r < 4; ++r)
            O0[((size_t)b * 256 + mg + r) * T_ + t] = v[r] + bias[mg + r];
        }
      }
    }
  }
}

// ---------------- fused rs_i + pw_{i+1} (serial trunk) ---------------------
// Stage 1: EXACT mm6<2,64> core/epilogue (y==0 res, y==1 skip). Res blocks
// additionally write the bf16 nv tile into LDS (As reuse, XOR-swizzled).
// Stage 2 (y==0 only): pw_{i+1}, M=512, K=128, B from LDS, A frags from
// global (L2-resident Wpw), EPI-1 epilogue (prelu + Y slot + GN1 stats).
// FLG: 2 = WF feat write in stage-1 res epilogue.
template <int FLG>
__global__ __launch_bounds__(256) void rsp(MMP p) {
  constexpr bool WF = (FLG & 2) != 0;
  constexpr int TN = 64;
  constexpr int NJ = 2;
  __shared__ unsigned short As[128 * 64];   // stage-1 A staging; then handoff [64t][128k]
  __shared__ unsigned short Bs[TN * 64];
  __shared__ float redw[8];
  const int b = blockIdx.z;
  const int m0 = blockIdx.y * 128;
  const int t0 = blockIdx.x * TN;
  const int tid = threadIdx.x;
  const int lane = tid & 63;
  const int w = tid >> 6;
  const int wm = w >> 1, wn = w & 1;
  const int lt = lane & 15, lg = lane >> 4;
  const int K = 512;
  const unsigned short* Ab = p.A0 + (size_t)m0 * K;
  const unsigned short* Bb = p.B0 + ((size_t)b * TP_ + t0) * K;
  const int srow8 = lane >> 3;
  const int skc   = ((lane & 7) ^ (lane >> 3)) * 8;

  f32x4 acc[4][NJ];
#pragma unroll
  for (int i = 0; i < 4; ++i)
#pragma unroll
    for (int j = 0; j < NJ; ++j) acc[i][j] = (f32x4){0.f, 0.f, 0.f, 0.f};

  for (int k0 = 0; k0 < K; k0 += 64) {
#pragma unroll
    for (int c = 0; c < 4; ++c) {
      const int ch = w * 4 + c;
      g2lds16(Ab + (size_t)(ch * 8 + srow8) * K + k0 + skc, &As[ch * 512]);
    }
#pragma unroll
    for (int c = 0; c < NJ; ++c) {
      const int ch = w * NJ + c;
      g2lds16(Bb + (size_t)(ch * 8 + srow8) * K + k0 + skc, &Bs[ch * 512]);
    }
    __syncthreads();
#pragma unroll
    for (int ks = 0; ks < 2; ++ks) {
      s8v bfr[NJ];
#pragma unroll
      for (int j = 0; j < NJ; ++j) {
        const int R = wn * (TN / 2) + j * 16 + lt;
        bfr[j] = *(const s8v*)&Bs[R * 64 + (((ks * 4 + lg) ^ (R & 7)) * 8)];
      }
#pragma unroll
      for (int i = 0; i < 4; ++i) {
        const int R = wm * 64 + i * 16 + lt;
        s8v af = *(const s8v*)&As[R * 64 + (((ks * 4 + lg) ^ (R & 7)) * 8)];
#pragma unroll
        for (int j = 0; j < NJ; ++j)
          acc[i][j] = __builtin_amdgcn_mfma_f32_16x16x32_bf16(af, bfr[j], acc[i][j], 0, 0, 0);
      }
    }
    __syncthreads();
  }

  // ---- stage-1 epilogue (EPI-2 semantics) + handoff for res blocks
  {
    float su, sq;
    stats_sum(p.si0, b, su, sq);
    const float mean = su * p.invN;
    const float rsv = rsqrtf(sq * p.invN - mean * mean + 1e-8f);
    const bool isRes = (m0 == 0);
#pragma unroll
    for (int i = 0; i < 4; ++i) {
      const int ml = wm * 64 + i * 16 + lg * 4;
      float cc[4];
#pragma unroll
      for (int r = 0; r < 4; ++r) {
        const int mgG = m0 + ml + r;
        cc[r] = p.Vc0[mgG] - mean * rsv * p.Uc0[mgG] +
                (isRes ? p.rb0[ml + r] : p.sb0[ml + r]);
      }
#pragma unroll
      for (int j = 0; j < NJ; ++j) {
        const int t = t0 + wn * 32 + j * 16 + lt;
        f32x4 v = acc[i][j];
        if (isRes) {
          float* ptr = p.O0a + ((size_t)b * TP_ + t) * 128 + ml;
          float4 old = *(float4*)ptr;
          float nv[4] = {old.x + rsv * v[0] + cc[0], old.y + rsv * v[1] + cc[1],
                         old.z + rsv * v[2] + cc[2], old.w + rsv * v[3] + cc[3]};
          *(float4*)ptr = make_float4(nv[0], nv[1], nv[2], nv[3]);
          u16x4 pk;
#pragma unroll
          for (int r = 0; r < 4; ++r) pk[r] = f2bf(nv[r]);
          *(u16x4*)(p.Obf0 + ((size_t)b * TP_ + t) * 128 + ml) = pk;
          // handoff: LDS tile [tl][128m], 8B units XOR-swizzled (pair-safe)
          const int tl = wn * 32 + j * 16 + lt;
          const int c4 = wm * 16 + i * 4 + lg;          // ml/4
          *(u16x4*)&As[tl * 128 + (c4 ^ (2 * (tl & 7))) * 4] = pk;
          if constexpr (WF) {
            if (t < T_) {
#pragma unroll
              for (int r = 0; r < 4; ++r)
                p.feat[((size_t)b * 128 + ml + r) * T_ + t] = nv[r];
            }
          }
        } else {
          float* ptr = p.O1a + ((size_t)b * TP_ + t) * 128 + ml;
          float4 old = *(float4*)ptr;
          *(float4*)ptr = make_float4(old.x + rsv * v[0] + cc[0],
                                      old.y + rsv * v[1] + cc[1],
                                      old.z + rsv * v[2] + cc[2],
                                      old.w + rsv * v[3] + cc[3]);
        }
      }
    }
  }

  // ---- stage 2: pw_{i+1} on the fresh res tile (res blocks only)
  if (blockIdx.y == 0) {
    __syncthreads();   // handoff tile complete
    const unsigned short* A2 = p.A1;   // Wpw_{i+1} [512][128]
    f32x4 acc2[8][4];
#pragma unroll
    for (int i2 = 0; i2 < 8; ++i2)
#pragma unroll
      for (int j2 = 0; j2 < 4; ++j2) acc2[i2][j2] = (f32x4){0.f, 0.f, 0.f, 0.f};
#pragma unroll
    for (int kk = 0; kk < 2; ++kk) {
#pragma unroll
      for (int ks = 0; ks < 2; ++ks) {
        s8v bv[4];
#pragma unroll
        for (int j2 = 0; j2 < 4; ++j2) {
          const int R2 = j2 * 16 + lt;
          const int q = kk * 8 + ks * 4 + lg;
          bv[j2] = *(const s8v*)&As[R2 * 128 + (q ^ (R2 & 7)) * 8];
        }
        s8v av[8];
#pragma unroll
        for (int i2 = 0; i2 < 8; ++i2) {
          const int R = w * 128 + i2 * 16 + lt;
          av[i2] = *(const s8v*)(A2 + (size_t)R * 128 + kk * 64 + ks * 32 + lg * 8);
        }
#pragma unroll
        for (int i2 = 0; i2 < 8; ++i2)
#pragma unroll
          for (int j2 = 0; j2 < 4; ++j2)
            acc2[i2][j2] = __builtin_amdgcn_mfma_f32_16x16x32_bf16(av[i2], bv[j2], acc2[i2][j2], 0, 0, 0);
      }
    }
    // EPI-1 epilogue: prelu -> Y slot + masked GN1 stats
    const float aO = p.al1[0];
    unsigned short* Yd = p.Obf1 + (size_t)b * YSST;
    float s1 = 0.f, s2 = 0.f;
#pragma unroll
    for (int i2 = 0; i2 < 8; ++i2) {
      const int mg = w * 128 + i2 * 16 + lg * 4;
      float4 bi = *(const float4*)(p.bias1 + mg);
      float bvv[4] = {bi.x, bi.y, bi.z, bi.w};
#pragma unroll
      for (int j2 = 0; j2 < 4; ++j2) {
        const int t = t0 + j2 * 16 + lt;
        f32x4 v = acc2[i2][j2];
        u16x4 pk;
#pragma unroll
        for (int r = 0; r < 4; ++r) {
          float f = v[r] + bvv[r];
          f = f >= 0.f ? f : aO * f;
          pk[r] = f2bf(f);
        }
        *(u16x4*)(Yd + (size_t)t * YROW + mg) = pk;
        if (t < T_) {
#pragma unroll
          for (int r = 0; r < 4; ++r) { float f = bf2f(pk[r]); s1 += f; s2 += f * f; }
        }
      }
    }
#pragma unroll
    for (int off = 32; off > 0; off >>= 1) {
      s1 += __shfl_xor(s1, off);
      s2 += __shfl_xor(s2, off);
    }
    if (lane == 0) { redw[w] = s1; redw[4 + w] = s2; }
    __syncthreads();
    if (tid == 0) {
      float* dst = p.so1 + (size_t)(blockIdx.x & (NSUB - 1)) * 8 + b * 2;
      atomicAdd(&dst[0], redw[0] + redw[1] + redw[2] + redw[3]);
      atomicAdd(&dst[1], redw[4] + redw[5] + redw[6] + redw[7]);
    }
  }
}

// ---------------- depthwise dilated conv, [t][h], unconditional loads ------
__global__ __launch_bounds__(256) void dw3(
    const unsigned short* __restrict__ Y, unsigned short* __restrict__ U,
    const float* __restrict__ dww0, const float* __restrict__ dww1,
    const float* __restrict__ dwb0, const float* __restrict__ dwb1,
    const float* __restrict__ g10, const float* __restrict__ g11,
    const float* __restrict__ b10, const float* __restrict__ b11,
    const float* __restrict__ p20, const float* __restrict__ p21,
    const float* __restrict__ sIn0, const float* __restrict__ sIn1, float invN,
    float* __restrict__ sOut0, float* __restrict__ sOut1, int dil, int halfY) {
  const int q = blockIdx.y;
  const bool br2 = q >= halfY;
  const int b = br2 ? q - halfY : q;
  const float* dww = br2 ? dww1 : dww0;
  const float* dwb = br2 ? dwb1 : dwb0;
  const float* g1  = br2 ? g11 : g10;
  const float* b1  = br2 ? b11 : b10;
  const float* p2p = br2 ? p21 : p20;
  const float* sIn = br2 ? sIn1 : sIn0;
  float* sOut      = br2 ? sOut1 : sOut0;
  const int tid = threadIdx.x;
  const int hc = (tid & 63) * 8;
  const int tbase = blockIdx.x * 16 + (tid >> 6) * 4;

  float su, sq2;
  stats_sum(sIn, b, su, sq2);
  const float mean = su * invN;
  const float rs = rsqrtf(sq2 * invN - mean * mean + 1e-8f);
  float sA[8], oA[8], w0[8], w1[8], w2[8], bb[8];
#pragma unroll
  for (int j = 0; j < 8; ++j) {
    sA[j] = rs * g1[hc + j];
    oA[j] = b1[hc + j] - mean * sA[j];
    w0[j] = dww[(hc + j) * 3 + 0];
    w1[j] = dww[(hc + j) * 3 + 1];
    w2[j] = dww[(hc + j) * 3 + 2];
    bb[j] = dwb[hc + j];
  }
  const float alpha = p2p[0];
  const unsigned short* Yb = Y + (size_t)q * YSST;
  unsigned short* Ub = U + (size_t)q * USST;

  s8v xm[4], x0[4], xp[4];
#pragma unroll
  for (int i = 0; i < 4; ++i) {
    const int t = tbase + i;
    xm[i] = *(const s8v*)(Yb + (size_t)(t - dil) * YROW + hc);
    x0[i] = *(const s8v*)(Yb + (size_t)t * YROW + hc);
    xp[i] = *(const s8v*)(Yb + (size_t)(t + dil) * YROW + hc);
  }

  float s1 = 0.f, s2 = 0.f;
#pragma unroll
  for (int i = 0; i < 4; ++i) {
    const int t = tbase + i;
    const bool vm = (t - dil >= 0), vp = (t + dil < T_);
    s8v out;
#pragma unroll
    for (int j = 0; j < 8; ++j) {
      float fm = vm ? (bf2f((unsigned short)xm[i][j]) * sA[j] + oA[j]) : 0.f;
      float f0 = bf2f((unsigned short)x0[i][j]) * sA[j] + oA[j];
      float fp = vp ? (bf2f((unsigned short)xp[i][j]) * sA[j] + oA[j]) : 0.f;
      float v = fmaf(w0[j], fm, fmaf(w1[j], f0, fmaf(w2[j], fp, bb[j])));
      v = v >= 0.f ? v : alpha * v;
      unsigned short u = f2bf(v);
      out[j] = (short)u;
      float f = bf2f(u);
      s1 += f; s2 += f * f;
    }
    *(s8v*)(Ub + (size_t)t * YROW + hc) = out;
  }
#pragma unroll
  for (int off = 32; off > 0; off >>= 1) {
    s1 += __shfl_xor(s1, off);
    s2 += __shfl_xor(s2, off);
  }
  __shared__ float red[8];
  const int lane = tid & 63, wv = tid >> 6;
  if (lane == 0) { red[wv] = s1; red[4 + wv] = s2; }
  __syncthreads();
  if (tid == 0) {
    float* dst = sOut + (size_t)(blockIdx.x & (NSUB - 1)) * 8 + b * 2;
    atomicAdd(&dst[0], red[0] + red[1] + red[2] + red[3]);
    atomicAdd(&dst[1], red[4] + red[5] + red[6] + red[7]);
  }
}

// ---------------------------------------------------------------------------
extern "C" void kernel_launch(void* const* d_in, const int* in_sizes, int n_in,
                              void* d_out, int out_size, void* d_ws, size_t ws_size,
                              hipStream_t stream) {
  (void)in_sizes; (void)n_in; (void)out_size; (void)ws_size;
  const float* input = (const float*)d_in[0];
  const float* ln1_g = (const float*)d_in[1];
  const float* ln1_b = (const float*)d_in[2];
  const float* bn1_w = (const float*)d_in[3];
  const float* bn1_b = (const float*)d_in[4];
  const float* pw_w  = (const float*)d_in[5];
  const float* pw_b  = (const float*)d_in[6];
  const float* dw_w  = (const float*)d_in[7];
  const float* dw_b  = (const float*)d_in[8];
  const float* res_w = (const float*)d_in[9];
  const float* res_b = (const float*)d_in[10];
  const float* sk_w  = (const float*)d_in[11];
  const float* sk_b  = (const float*)d_in[12];
  const float* p1    = (const float*)d_in[13];
  const float* p2    = (const float*)d_in[14];
  const float* n1g   = (const float*)d_in[15];
  const float* n1b   = (const float*)d_in[16];
  const float* n2g   = (const float*)d_in[17];
  const float* n2b   = (const float*)d_in[18];
  const float* h1_p  = (const float*)d_in[19];
  const float* h1_w  = (const float*)d_in[20];
  const float* h1_b  = (const float*)d_in[21];
  const float* h2_p  = (const float*)d_in[22];
  const float* h2_w  = (const float*)d_in[23];
  const float* h2_b  = (const float*)d_in[24];

  float* out1 = (float*)d_out;
  float* out2 = out1 + 4096000;   // [4,256,4000]
  float* feat = out1 + 8192000;   // [4,128,4000]

  char* base = (char*)d_ws;
  float* OUTS  = (float*)base;                  base += (size_t)B_ * TP_ * 128 * 4;
  float* SKIP  = (float*)base;                  base += (size_t)B_ * TP_ * 128 * 4;
  float* OUT2  = (float*)base;                  base += (size_t)B_ * TP_ * 128 * 4;
  float* SKIP2 = (float*)base;                  base += (size_t)B_ * TP_ * 128 * 4;
  unsigned short* OUTbf  = (unsigned short*)base; base += (size_t)B_ * TP_ * 128 * 2;
  unsigned short* OUT2bf = (unsigned short*)base; base += (size_t)B_ * TP_ * 128 * 2;
  unsigned short* Ybuf = (unsigned short*)base; base += (size_t)8 * YSST * 2;  // 8 slots + halo
  unsigned short* Ubuf = (unsigned short*)base; base += (size_t)8 * USST * 2;  // 8 slots
  unsigned short* Xt   = (unsigned short*)base; base += (size_t)B_ * TP_ * 256 * 2;
  unsigned short* SKbf = (unsigned short*)base; base += (size_t)2 * B_ * TP_ * 128 * 2;
  unsigned short* Wpw  = (unsigned short*)base; base += (size_t)32 * 512 * 128 * 2;
  unsigned short* Wg   = (unsigned short*)base; base += (size_t)32 * 256 * 512 * 2;
  unsigned short* Wbn  = (unsigned short*)base; base += (size_t)128 * 256 * 2;
  unsigned short* Wh1  = (unsigned short*)base; base += (size_t)256 * 128 * 2;
  unsigned short* Wh2  = (unsigned short*)base; base += (size_t)256 * 128 * 2;
  float* UVu   = (float*)base;                  base += (size_t)32 * 256 * 4;
  float* UVv   = (float*)base;                  base += (size_t)32 * 256 * 4;
  float* STATS = (float*)base;

  unsigned short* YbufD = Ybuf + (size_t)YHAL * YROW;  // data base (halo before)
  const int npr = B_ * TP_ * 128;

  hipMemsetAsync(STATS, 0, (size_t)65 * SLOTW * sizeof(float), stream);
  hipMemsetAsync(SKIP, 0, (size_t)B_ * TP_ * 128 * sizeof(float), stream);

  const float invN_in = 1.0f / (256.0f * 4000.0f);
  const float invN_h  = 1.0f / (512.0f * 4000.0f);

  // weight prep
  cvt_bf<<<2048, 256, 0, stream>>>(pw_w, Wpw, 32 * 512 * 128);
  cvt_bf<<<128, 256, 0, stream>>>(bn1_w, Wbn, 128 * 256);
  cvt_bf<<<128, 256, 0, stream>>>(h1_w, Wh1, 256 * 128);
  cvt_bf<<<128, 256, 0, stream>>>(h2_w, Wh2, 256 * 128);
  fold_rs<<<32 * 256, 256, 0, stream>>>(res_w, sk_w, n2g, n2b, Wg, UVu, UVv);

  // input GN -> bf16 [t][256] -> bottleneck GEMM
  gn_stats<<<dim3(64, B_), 256, 0, stream>>>(input, STATS, 256 * T_);
  tin<<<dim3(63, 4, B_), 256, 0, stream>>>(input, Xt, ln1_g, ln1_b, STATS, invN_in);
  {
    MMP q{}; q.A0 = Wbn; q.B0 = Xt; q.bias0 = bn1_b; q.O0a = OUTS; q.Obf0 = OUTbf;
    q.K = 256;
    mm6<0, 128, 0><<<dim3(32, 1, B_), 256, 0, stream>>>(q);
  }

  auto pw_one = [&](int i) {
    MMP q{}; q.A0 = Wpw + (size_t)i * 512 * 128; q.B0 = OUTbf;
    q.bias0 = pw_b + (size_t)i * 512; q.Obf0 = YbufD; q.al0 = p1 + i;
    q.so0 = STATS + (size_t)(1 + 2 * i) * SLOTW; q.K = 128;
    mm6<1, 128, 0><<<dim3(32, 4, B_), 256, 0, stream>>>(q);
  };
  auto dw_one = [&](int i) {
    float* sA = STATS + (size_t)(1 + 2 * i) * SLOTW;
    float* sB = STATS + (size_t)(2 + 2 * i) * SLOTW;
    dw3<<<dim3(250, B_), 256, 0, stream>>>(
        YbufD, Ubuf, dw_w + (size_t)i * 512 * 3, nullptr,
        dw_b + (size_t)i * 512, nullptr, n1g + (size_t)i * 512, nullptr,
        n1b + (size_t)i * 512, nullptr, p2 + i, nullptr, sA, nullptr, invN_h,
        sB, nullptr, 1 << (i & 7), 99);
  };
  auto rs_one = [&](int i, int flg) {
    MMP q{}; q.A0 = Wg + (size_t)i * 256 * 512; q.B0 = Ubuf;
    q.O0a = OUTS; q.O1a = SKIP; q.Obf0 = OUTbf;
    q.si0 = STATS + (size_t)(2 + 2 * i) * SLOTW; q.invN = invN_h;
    q.Uc0 = UVu + (size_t)i * 256; q.Vc0 = UVv + (size_t)i * 256;
    q.rb0 = res_b + (size_t)i * 128; q.sb0 = sk_b + (size_t)i * 128;
    q.feat = feat; q.dupO0 = OUT2; q.dupObf = OUT2bf; q.dupO1 = SKIP2;
    q.K = 512;
    if (flg == 4) mm6<2, 64, 4><<<dim3(64, 2, B_), 256, 0, stream>>>(q);
    else          mm6<2, 64, 0><<<dim3(64, 2, B_), 256, 0, stream>>>(q);
  };

  // ---- serial trunk: pw0, dw0, then 15x (fused rs_i+pw_{i+1}, dw_{i+1}), rs15
  pw_one(0);
  dw_one(0);
  for (int i = 0; i < 15; ++i) {
    MMP q{};
    q.A0 = Wg + (size_t)i * 256 * 512; q.B0 = Ubuf;
    q.O0a = OUTS; q.O1a = SKIP; q.Obf0 = OUTbf;
    q.si0 = STATS + (size_t)(2 + 2 * i) * SLOTW; q.invN = invN_h;
    q.Uc0 = UVu + (size_t)i * 256; q.Vc0 = UVv + (size_t)i * 256;
    q.rb0 = res_b + (size_t)i * 128; q.sb0 = sk_b + (size_t)i * 128;
    q.feat = feat;
    q.A1 = Wpw + (size_t)(i + 1) * 512 * 128;
    q.bias1 = pw_b + (size_t)(i + 1) * 512;
    q.al1 = p1 + (i + 1);
    q.so1 = STATS + (size_t)(1 + 2 * (i + 1)) * SLOTW;
    q.Obf1 = YbufD;
    q.K = 512;
    if (i == 7) rsp<2><<<dim3(64, 2, B_), 256, 0, stream>>>(q);
    else        rsp<0><<<dim3(64, 2, B_), 256, 0, stream>>>(q);
    dw_one(i + 1);
  }
  rs_one(15, 4);   // standalone, writes fork copies (DUP)

  // ---- paired blocks: branch1 = 16+j, branch2 = 24+j
  for (int j = 0; j < 8; ++j) {
    const int i1 = 16 + j, i2 = 24 + j;
    float* sA1 = STATS + (size_t)(1 + 2 * i1) * SLOTW;
    float* sB1 = STATS + (size_t)(2 + 2 * i1) * SLOTW;
    float* sA2 = STATS + (size_t)(1 + 2 * i2) * SLOTW;
    float* sB2 = STATS + (size_t)(2 + 2 * i2) * SLOTW;
    {
      MMP q{};
      q.A0 = Wpw + (size_t)i1 * 512 * 128; q.A1 = Wpw + (size_t)i2 * 512 * 128;
      q.B0 = OUTbf; q.B1 = OUT2bf;
      q.bias0 = pw_b + (size_t)i1 * 512; q.bias1 = pw_b + (size_t)i2 * 512;
      q.Obf0 = YbufD; q.Obf1 = YbufD + 4 * YSST;
      q.al0 = p1 + i1; q.al1 = p1 + i2;
      q.so0 = sA1; q.so1 = sA2; q.K = 128;
      mm6<1, 128, 1><<<dim3(32, 4, 2 * B_), 256, 0, stream>>>(q);
    }
    dw3<<<dim3(250, 2 * B_), 256, 0, stream>>>(
        YbufD, Ubuf,
        dw_w + (size_t)i1 * 512 * 3, dw_w + (size_t)i2 * 512 * 3,
        dw_b + (size_t)i1 * 512, dw_b + (size_t)i2 * 512,
        n1g + (size_t)i1 * 512, n1g + (size_t)i2 * 512,
        n1b + (size_t)i1 * 512, n1b + (size_t)i2 * 512,
        p2 + i1, p2 + i2, sA1, sA2, invN_h, sB1, sB2, 1 << (j & 7), B_);
    {
      MMP q{};
      q.A0 = Wg + (size_t)i1 * 256 * 512; q.A1 = Wg + (size_t)i2 * 256 * 512;
      q.B0 = Ubuf; q.B1 = Ubuf + 4 * USST;
      q.O0a = OUTS; q.O0b = OUT2; q.O1a = SKIP; q.O1b = SKIP2;
      q.Obf0 = OUTbf; q.Obf1 = OUT2bf;
      q.si0 = sB1; q.si1 = sB2; q.invN = invN_h;
      q.Uc0 = UVu + (size_t)i1 * 256; q.Uc1 = UVu + (size_t)i2 * 256;
      q.Vc0 = UVv + (size_t)i1 * 256; q.Vc1 = UVv + (size_t)i2 * 256;
      q.rb0 = res_b + (size_t)i1 * 128; q.rb1 = res_b + (size_t)i2 * 128;
      q.sb0 = sk_b + (size_t)i1 * 128; q.sb1 = sk_b + (size_t)i2 * 128;
      q.K = 512;
      mm6<2, 128, 1><<<dim3(32, 2, 2 * B_), 256, 0, stream>>>(q);
    }
  }

  // ---- heads (both in one pass)
  prelu2<<<2048, 256, 0, stream>>>(SKIP, SKIP2, SKbf, h1_p, h2_p, npr);
  {
    MMP q{};
    q.A0 = Wh1; q.A1 = Wh2;
    q.B0 = SKbf; q.B1 = SKbf + npr;
    q.bias0 = h1_b; q.bias1 = h2_b;
    q.O0a = out1; q.O0b = out2; q.K = 128;
    mm6<3, 128, 1><<<dim3(32, 2, 2 * B_), 256, 0, stream>>>(q);
  }
}

// Round 11
// 1243.759 us; speedup vs baseline: 1.0535x; 1.0535x over previous
//
#include <hip/hip_runtime.h>
#include <hip/hip_bf16.h>

// ---------------------------------------------------------------------------
// Conv-TasNet TCN, bf16-MFMA v10 = r8 (proven 1268us) + BK=128 on K-rich GEMMs.
// mm6<EPI,TN,FLG,BK>: BK=64 identical to r8; BK=128 stages two 64-k planes
// per barrier (halves K-steps for rs K=512 / bn1 K=256). Same swizzle idiom
// per plane -> bit-identical math. pw/heads keep BK=64 (residency).
// ---------------------------------------------------------------------------

#define T_  4000
#define TP_ 4096
#define B_  4
#define YHAL 128
#define YROW 512
#define YSST ((size_t)(TP_ + 2 * YHAL) * YROW)
#define USST ((size_t)TP_ * YROW)
#define NSUB 64
#define SLOTW (NSUB * 8)

typedef __attribute__((ext_vector_type(8))) short  s8v;
typedef __attribute__((ext_vector_type(4))) float  f32x4;
typedef __attribute__((ext_vector_type(4))) unsigned short u16x4;

__device__ __forceinline__ float bf2f(unsigned short u) {
  unsigned int i = ((unsigned int)u) << 16;
  float f; __builtin_memcpy(&f, &i, 4); return f;
}
__device__ __forceinline__ unsigned short f2bf(float f) {
  unsigned int i; __builtin_memcpy(&i, &f, 4);
  unsigned int r = i + 0x7fffu + ((i >> 16) & 1u);
  return (unsigned short)(r >> 16);
}

__device__ __forceinline__ void g2lds16(const void* g, void* l) {
  __builtin_amdgcn_global_load_lds(
      (const __attribute__((address_space(1))) unsigned int*)g,
      (__attribute__((address_space(3))) unsigned int*)l, 16, 0, 0);
}

// consumer-side: sum the 64 sub-slot partials of one stats slot (per-wave).
__device__ __forceinline__ void stats_sum(const float* __restrict__ si, int b,
                                          float& u, float& q) {
  const int lane = threadIdx.x & 63;
  u = si[lane * 8 + b * 2 + 0];
  q = si[lane * 8 + b * 2 + 1];
#pragma unroll
  for (int off = 32; off > 0; off >>= 1) {
    u += __shfl_xor(u, off);
    q += __shfl_xor(q, off);
  }
}

// ---------------- per-sample sum/sumsq over contiguous [C*T] ---------------
__global__ __launch_bounds__(256) void gn_stats(const float* __restrict__ X,
                                                float* __restrict__ statsOut, int n) {
  const int b = blockIdx.y;
  const float4* xp = (const float4*)(X + (size_t)b * n);
  const int n4 = n >> 2;
  float s1 = 0.f, s2 = 0.f;
  for (int idx = blockIdx.x * 256 + threadIdx.x; idx < n4; idx += gridDim.x * 256) {
    float4 v = xp[idx];
    s1 += v.x + v.y + v.z + v.w;
    s2 += v.x * v.x + v.y * v.y + v.z * v.z + v.w * v.w;
  }
#pragma unroll
  for (int off = 32; off > 0; off >>= 1) {
    s1 += __shfl_xor(s1, off);
    s2 += __shfl_xor(s2, off);
  }
  __shared__ float red[8];
  const int lane = threadIdx.x & 63, wv = threadIdx.x >> 6;
  if (lane == 0) { red[wv] = s1; red[4 + wv] = s2; }
  __syncthreads();
  if (threadIdx.x == 0) {
    float* dst = statsOut + (size_t)(blockIdx.x & (NSUB - 1)) * 8 + b * 2;
    atomicAdd(&dst[0], red[0] + red[1] + red[2] + red[3]);
    atomicAdd(&dst[1], red[4] + red[5] + red[6] + red[7]);
  }
}

// ---------------- weight prep ----------------------------------------------
__global__ __launch_bounds__(256) void cvt_bf(const float* __restrict__ s,
                                              unsigned short* __restrict__ d, int n) {
  for (int i = blockIdx.x * 256 + threadIdx.x; i < n; i += gridDim.x * 256)
    d[i] = f2bf(s[i]);
}

__global__ __launch_bounds__(256) void fold_rs(
    const float* __restrict__ rw, const float* __restrict__ sw,
    const float* __restrict__ g2a, const float* __restrict__ b2a,
    unsigned short* __restrict__ Wg, float* __restrict__ Ucb,
    float* __restrict__ Vcb) {
  const int row = blockIdx.x;                 // i*256 + m
  const int i = row >> 8, m = row & 255;
  const float* src = (m < 128) ? rw + ((size_t)i * 128 + m) * 512
                               : sw + ((size_t)i * 128 + (m - 128)) * 512;
  const float* g = g2a + (size_t)i * 512;
  const float* bb = b2a + (size_t)i * 512;
  unsigned short* dst = Wg + (size_t)row * 512;
  float u = 0.f, v = 0.f;
  for (int h = threadIdx.x; h < 512; h += 256) {
    float wgt = src[h] * g[h];
    dst[h] = f2bf(wgt);
    u += wgt; v += src[h] * bb[h];
  }
#pragma unroll
  for (int off = 32; off > 0; off >>= 1) {
    u += __shfl_xor(u, off);
    v += __shfl_xor(v, off);
  }
  __shared__ float red[8];
  const int lane = threadIdx.x & 63, wv = threadIdx.x >> 6;
  if (lane == 0) { red[wv] = u; red[4 + wv] = v; }
  __syncthreads();
  if (threadIdx.x == 0) {
    Ucb[row] = red[0] + red[1] + red[2] + red[3];
    Vcb[row] = red[4] + red[5] + red[6] + red[7];
  }
}

// both heads' prelu+cvt in one launch
__global__ __launch_bounds__(256) void prelu2(const float* __restrict__ S0,
                                              const float* __restrict__ S1,
                                              unsigned short* __restrict__ D,
                                              const float* __restrict__ a0p,
                                              const float* __restrict__ a1p, int n) {
  const float a0 = a0p[0], a1 = a1p[0];
  for (int i = blockIdx.x * 256 + threadIdx.x; i < 2 * n; i += gridDim.x * 256) {
    float v = (i < n) ? S0[i] : S1[i - n];
    float a = (i < n) ? a0 : a1;
    v = v >= 0.f ? v : a * v;
    D[i] = f2bf(v);
  }
}

// ---------------- input transpose + GN affine + bf16 -----------------------
__global__ __launch_bounds__(256) void tin(const float* __restrict__ X,
                                           unsigned short* __restrict__ Xt,
                                           const float* __restrict__ g,
                                           const float* __restrict__ bt,
                                           const float* __restrict__ sIn, float invN) {
  const int b = blockIdx.z, c0 = blockIdx.y * 64, t0 = blockIdx.x * 64;
  __shared__ float tile[64][65];
  const int tid = threadIdx.x;
  float su, sq;
  stats_sum(sIn, b, su, sq);
  const float mean = su * invN;
  const float rs = rsqrtf(sq * invN - mean * mean + 1e-8f);
  {
    const int cl = tid >> 2, tq = (tid & 3) * 16;
    const float* Xr = X + ((size_t)b * 256 + c0 + cl) * T_;
#pragma unroll
    for (int j = 0; j < 4; ++j) {
      int tt = t0 + tq + j * 4;
      float4 v;
      if (tt + 3 < T_) v = *(const float4*)(Xr + tt);
      else {
        v.x = (tt + 0 < T_) ? Xr[tt + 0] : 0.f;
        v.y = (tt + 1 < T_) ? Xr[tt + 1] : 0.f;
        v.z = (tt + 2 < T_) ? Xr[tt + 2] : 0.f;
        v.w = (tt + 3 < T_) ? Xr[tt + 3] : 0.f;
      }
      tile[cl][tq + j * 4 + 0] = v.x; tile[cl][tq + j * 4 + 1] = v.y;
      tile[cl][tq + j * 4 + 2] = v.z; tile[cl][tq + j * 4 + 3] = v.w;
    }
  }
  __syncthreads();
  {
    const int tl = tid >> 2, cq = (tid & 3) * 16;
    const int t = t0 + tl;
    if (t < T_) {
      unsigned short* dst = Xt + ((size_t)b * TP_ + t) * 256 + c0 + cq;
      s8v u0, u1;
#pragma unroll
      for (int j = 0; j < 16; ++j) {
        int c = c0 + cq + j;
        float sc = rs * g[c];
        float oc = bt[c] - mean * sc;
        unsigned short uu = f2bf(tile[cq + j][tl] * sc + oc);
        if (j < 8) u0[j] = (short)uu; else u1[j - 8] = (short)uu;
      }
      *(s8v*)dst = u0;
      *(s8v*)(dst + 8) = u1;
    }
  }
}

// ---------------- mm6 params ------------------------------------------------
struct MMP {
  const unsigned short *A0, *A1, *B0, *B1;
  const float *bias0, *bias1;
  float *O0a, *O0b, *O1a, *O1b;
  unsigned short *Obf0, *Obf1;
  const float *al0, *al1;
  float *so0, *so1;
  const float *si0, *si1;
  const float *Uc0, *Uc1, *Vc0, *Vc1, *rb0, *rb1, *sb0, *sb1;
  float* feat;
  float* dupO0; unsigned short* dupObf; float* dupO1;
  int K; float invN;
};

// ---------------- clean bf16 MFMA GEMM, 128m x TNt x BKk, single-buffer ----
// BK in {64,128}; LDS holds KH=BK/64 independent 64-k planes, each staged and
// read with the identical XOR-swizzle idiom (KH=1 == r8 code exactly).
// EPI 0: O0 fp32 [t][128] = v+bias, Obf shadow                (bn1)
// EPI 1: prelu -> Obf bf16 Y-slot (halo stride YSST) + GN stats (pw)
// EPI 2: GN2-folded; y==0: res RMW O0 + shadow; y==1: skip RMW O1
//        WF: also write feat; DUP: also write fork copies
// EPI 3: masked fp32 scatter O0[b][256][4000] = v+bias         (heads)
// FLG: 1=PAIR (blockIdx.z >= gridDim.z/2 -> branch-2 pointers)
template <int EPI, int TN, int FLG, int BK>
__global__ __launch_bounds__(256) void mm6(MMP p) {
  constexpr bool PAIR = (FLG & 1) != 0;
  constexpr bool WF   = (FLG & 2) != 0;
  constexpr bool DUPF = (FLG & 4) != 0;
  constexpr int NJ = TN / 32;
  constexpr int KH = BK / 64;
  __shared__ unsigned short As[KH * 128 * 64];
  __shared__ unsigned short Bs[KH * TN * 64];
  __shared__ float redw[8];
  int b = blockIdx.z; bool br2 = false;
  if constexpr (PAIR) {
    const int h = gridDim.z >> 1;
    if (b >= h) { br2 = true; b -= h; }
  }
  const int K = p.K;
  const unsigned short* A  = br2 ? p.A1 : p.A0;
  const unsigned short* Bm = br2 ? p.B1 : p.B0;
  const int m0 = blockIdx.y * 128;
  const int t0 = blockIdx.x * TN;
  const int tid = threadIdx.x;
  const int lane = tid & 63;
  const int w = tid >> 6;
  const int wm = w >> 1, wn = w & 1;
  const int lt = lane & 15, lg = lane >> 4;
  const unsigned short* Ab = A + (size_t)m0 * K;
  const unsigned short* Bb = Bm + ((size_t)b * TP_ + t0) * K;
  const int srow8 = lane >> 3;
  const int skc   = ((lane & 7) ^ (lane >> 3)) * 8;

  f32x4 acc[4][NJ];
#pragma unroll
  for (int i = 0; i < 4; ++i)
#pragma unroll
    for (int j = 0; j < NJ; ++j) acc[i][j] = (f32x4){0.f, 0.f, 0.f, 0.f};

  for (int k0 = 0; k0 < K; k0 += BK) {
#pragma unroll
    for (int kh = 0; kh < KH; ++kh) {
#pragma unroll
      for (int c = 0; c < 4; ++c) {
        const int ch = w * 4 + c;
        g2lds16(Ab + (size_t)(ch * 8 + srow8) * K + k0 + kh * 64 + skc,
                &As[kh * 8192 + ch * 512]);
      }
#pragma unroll
      for (int c = 0; c < NJ; ++c) {
        const int ch = w * NJ + c;
        g2lds16(Bb + (size_t)(ch * 8 + srow8) * K + k0 + kh * 64 + skc,
                &Bs[kh * TN * 64 + ch * 512]);
      }
    }
    __syncthreads();
#pragma unroll
    for (int kss = 0; kss < 2 * KH; ++kss) {
      const int kh = kss >> 1, ks = kss & 1;
      s8v bfr[NJ];
#pragma unroll
      for (int j = 0; j < NJ; ++j) {
        const int R = wn * (TN / 2) + j * 16 + lt;
        bfr[j] = *(const s8v*)&Bs[kh * TN * 64 + R * 64 + (((ks * 4 + lg) ^ (R & 7)) * 8)];
      }
#pragma unroll
      for (int i = 0; i < 4; ++i) {
        const int R = wm * 64 + i * 16 + lt;
        s8v af = *(const s8v*)&As[kh * 8192 + R * 64 + (((ks * 4 + lg) ^ (R & 7)) * 8)];
#pragma unroll
        for (int j = 0; j < NJ; ++j)
          acc[i][j] = __builtin_amdgcn_mfma_f32_16x16x32_bf16(af, bfr[j], acc[i][j], 0, 0, 0);
      }
    }
    __syncthreads();
  }

  // ---- epilogues. D row m = m0 + wm*64 + i*16 + lg*4 + r,
  //                 D col t = t0 + wn*(TN/2) + j*16 + lt
  if constexpr (EPI == 0) {
    const float* bias = p.bias0;
#pragma unroll
    for (int i = 0; i < 4; ++i) {
      const int mg = m0 + wm * 64 + i * 16 + lg * 4;
      float4 bi = *(const float4*)(bias + mg);
#pragma unroll
      for (int j = 0; j < NJ; ++j) {
        const int t = t0 + wn * (TN / 2) + j * 16 + lt;
        f32x4 v = acc[i][j];
        float nv[4] = {v[0] + bi.x, v[1] + bi.y, v[2] + bi.z, v[3] + bi.w};
        *(float4*)(p.O0a + ((size_t)b * TP_ + t) * 128 + mg) =
            make_float4(nv[0], nv[1], nv[2], nv[3]);
        u16x4 pk;
#pragma unroll
        for (int r = 0; r < 4; ++r) pk[r] = f2bf(nv[r]);
        *(u16x4*)(p.Obf0 + ((size_t)b * TP_ + t) * 128 + mg) = pk;
      }
    }
  } else if constexpr (EPI == 1) {
    const float* bias = br2 ? p.bias1 : p.bias0;
    unsigned short* Obf = (br2 ? p.Obf1 : p.Obf0) + (size_t)b * YSST;
    const float aO = (br2 ? p.al1 : p.al0)[0];
    float* so = br2 ? p.so1 : p.so0;
    float s1 = 0.f, s2 = 0.f;
#pragma unroll
    for (int i = 0; i < 4; ++i) {
      const int mg = m0 + wm * 64 + i * 16 + lg * 4;
      float4 bi = *(const float4*)(bias + mg);
      float bv[4] = {bi.x, bi.y, bi.z, bi.w};
#pragma unroll
      for (int j = 0; j < NJ; ++j) {
        const int t = t0 + wn * (TN / 2) + j * 16 + lt;
        f32x4 v = acc[i][j];
        u16x4 pk;
#pragma unroll
        for (int r = 0; r < 4; ++r) {
          float f = v[r] + bv[r];
          f = f >= 0.f ? f : aO * f;
          pk[r] = f2bf(f);
        }
        *(u16x4*)(Obf + (size_t)t * YROW + mg) = pk;
        if (t < T_) {
#pragma unroll
          for (int r = 0; r < 4; ++r) { float f = bf2f(pk[r]); s1 += f; s2 += f * f; }
        }
      }
    }
#pragma unroll
    for (int off = 32; off > 0; off >>= 1) {
      s1 += __shfl_xor(s1, off);
      s2 += __shfl_xor(s2, off);
    }
    if (lane == 0) { redw[w] = s1; redw[4 + w] = s2; }
    __syncthreads();
    if (tid == 0) {
      float* dst = so + (size_t)(blockIdx.x & (NSUB - 1)) * 8 + b * 2;
      atomicAdd(&dst[0], redw[0] + redw[1] + redw[2] + redw[3]);
      atomicAdd(&dst[1], redw[4] + redw[5] + redw[6] + redw[7]);
    }
  } else if constexpr (EPI == 2) {
    float* O0 = br2 ? p.O0b : p.O0a;
    float* O1 = br2 ? p.O1b : p.O1a;
    unsigned short* Obf = br2 ? p.Obf1 : p.Obf0;
    const float* si = br2 ? p.si1 : p.si0;
    const float* Uc = br2 ? p.Uc1 : p.Uc0;
    const float* Vc = br2 ? p.Vc1 : p.Vc0;
    const float* rb = br2 ? p.rb1 : p.rb0;
    const float* sb = br2 ? p.sb1 : p.sb0;
    float su, sq;
    stats_sum(si, b, su, sq);
    const float mean = su * p.invN;
    const float rsv = rsqrtf(sq * p.invN - mean * mean + 1e-8f);
    const bool isRes = (m0 == 0);
#pragma unroll
    for (int i = 0; i < 4; ++i) {
      const int ml = wm * 64 + i * 16 + lg * 4;   // 0..127 local
      float cc[4];
#pragma unroll
      for (int r = 0; r < 4; ++r) {
        const int mgG = m0 + ml + r;
        cc[r] = Vc[mgG] - mean * rsv * Uc[mgG] + (isRes ? rb[ml + r] : sb[ml + r]);
      }
#pragma unroll
      for (int j = 0; j < NJ; ++j) {
        const int t = t0 + wn * (TN / 2) + j * 16 + lt;
        f32x4 v = acc[i][j];
        if (isRes) {
          float* ptr = O0 + ((size_t)b * TP_ + t) * 128 + ml;
          float4 old = *(float4*)ptr;
          float nv[4] = {old.x + rsv * v[0] + cc[0], old.y + rsv * v[1] + cc[1],
                         old.z + rsv * v[2] + cc[2], old.w + rsv * v[3] + cc[3]};
          *(float4*)ptr = make_float4(nv[0], nv[1], nv[2], nv[3]);
          u16x4 pk;
#pragma unroll
          for (int r = 0; r < 4; ++r) pk[r] = f2bf(nv[r]);
          *(u16x4*)(Obf + ((size_t)b * TP_ + t) * 128 + ml) = pk;
          if constexpr (DUPF) {
            *(float4*)(p.dupO0 + ((size_t)b * TP_ + t) * 128 + ml) =
                make_float4(nv[0], nv[1], nv[2], nv[3]);
            *(u16x4*)(p.dupObf + ((size_t)b * TP_ + t) * 128 + ml) = pk;
          }
          if constexpr (WF) {
            if (t < T_) {
#pragma unroll
              for (int r = 0; r < 4; ++r)
                p.feat[((size_t)b * 128 + ml + r) * T_ + t] = nv[r];
            }
          }
        } else {
          float* ptr = O1 + ((size_t)b * TP_ + t) * 128 + ml;
          float4 old = *(float4*)ptr;
          float nv[4] = {old.x + rsv * v[0] + cc[0], old.y + rsv * v[1] + cc[1],
                         old.z + rsv * v[2] + cc[2], old.w + rsv * v[3] + cc[3]};
          *(float4*)ptr = make_float4(nv[0], nv[1], nv[2], nv[3]);
          if constexpr (DUPF) {
            *(float4*)(p.dupO1 + ((size_t)b * TP_ + t) * 128 + ml) =
                make_float4(nv[0], nv[1], nv[2], nv[3]);
          }
        }
      }
    }
  } else {  // EPI 3: heads scatter to [b][256][4000]
    float* O0 = br2 ? p.O0b : p.O0a;
    const float* bias = br2 ? p.bias1 : p.bias0;
#pragma unroll
    for (int i = 0; i < 4; ++i) {
      const int mg = m0 + wm * 64 + i * 16 + lg * 4;
#pragma unroll
      for (int j = 0; j < NJ; ++j) {
        const int t = t0 + wn * (TN / 2) + j * 16 + lt;
        if (t < T_) {
          f32x4 v = acc[i][j];
#pragma unroll
          for (int r = 0; r < 4; ++r)
            O0[((size_t)b * 256 + mg + r) * T_ + t] = v[r] + bias[mg + r];
        }
      }
    }
  }
}

// ---------------- depthwise dilated conv, [t][h], unconditional loads ------
__global__ __launch_bounds__(256) void dw3(
    const unsigned short* __restrict__ Y, unsigned short* __restrict__ U,
    const float* __restrict__ dww0, const float* __restrict__ dww1,
    const float* __restrict__ dwb0, const float* __restrict__ dwb1,
    const float* __restrict__ g10, const float* __restrict__ g11,
    const float* __restrict__ b10, const float* __restrict__ b11,
    const float* __restrict__ p20, const float* __restrict__ p21,
    const float* __restrict__ sIn0, const float* __restrict__ sIn1, float invN,
    float* __restrict__ sOut0, float* __restrict__ sOut1, int dil, int halfY) {
  const int q = blockIdx.y;
  const bool br2 = q >= halfY;
  const int b = br2 ? q - halfY : q;
  const float* dww = br2 ? dww1 : dww0;
  const float* dwb = br2 ? dwb1 : dwb0;
  const float* g1  = br2 ? g11 : g10;
  const float* b1  = br2 ? b11 : b10;
  const float* p2p = br2 ? p21 : p20;
  const float* sIn = br2 ? sIn1 : sIn0;
  float* sOut      = br2 ? sOut1 : sOut0;
  const int tid = threadIdx.x;
  const int hc = (tid & 63) * 8;
  const int tbase = blockIdx.x * 16 + (tid >> 6) * 4;

  float su, sq2;
  stats_sum(sIn, b, su, sq2);
  const float mean = su * invN;
  const float rs = rsqrtf(sq2 * invN - mean * mean + 1e-8f);
  float sA[8], oA[8], w0[8], w1[8], w2[8], bb[8];
#pragma unroll
  for (int j = 0; j < 8; ++j) {
    sA[j] = rs * g1[hc + j];
    oA[j] = b1[hc + j] - mean * sA[j];
    w0[j] = dww[(hc + j) * 3 + 0];
    w1[j] = dww[(hc + j) * 3 + 1];
    w2[j] = dww[(hc + j) * 3 + 2];
    bb[j] = dwb[hc + j];
  }
  const float alpha = p2p[0];
  const unsigned short* Yb = Y + (size_t)q * YSST;
  unsigned short* Ub = U + (size_t)q * USST;

  s8v xm[4], x0[4], xp[4];
#pragma unroll
  for (int i = 0; i < 4; ++i) {
    const int t = tbase + i;
    xm[i] = *(const s8v*)(Yb + (size_t)(t - dil) * YROW + hc);
    x0[i] = *(const s8v*)(Yb + (size_t)t * YROW + hc);
    xp[i] = *(const s8v*)(Yb + (size_t)(t + dil) * YROW + hc);
  }

  float s1 = 0.f, s2 = 0.f;
#pragma unroll
  for (int i = 0; i < 4; ++i) {
    const int t = tbase + i;
    const bool vm = (t - dil >= 0), vp = (t + dil < T_);
    s8v out;
#pragma unroll
    for (int j = 0; j < 8; ++j) {
      float fm = vm ? (bf2f((unsigned short)xm[i][j]) * sA[j] + oA[j]) : 0.f;
      float f0 = bf2f((unsigned short)x0[i][j]) * sA[j] + oA[j];
      float fp = vp ? (bf2f((unsigned short)xp[i][j]) * sA[j] + oA[j]) : 0.f;
      float v = fmaf(w0[j], fm, fmaf(w1[j], f0, fmaf(w2[j], fp, bb[j])));
      v = v >= 0.f ? v : alpha * v;
      unsigned short u = f2bf(v);
      out[j] = (short)u;
      float f = bf2f(u);
      s1 += f; s2 += f * f;
    }
    *(s8v*)(Ub + (size_t)t * YROW + hc) = out;
  }
#pragma unroll
  for (int off = 32; off > 0; off >>= 1) {
    s1 += __shfl_xor(s1, off);
    s2 += __shfl_xor(s2, off);
  }
  __shared__ float red[8];
  const int lane = tid & 63, wv = tid >> 6;
  if (lane == 0) { red[wv] = s1; red[4 + wv] = s2; }
  __syncthreads();
  if (tid == 0) {
    float* dst = sOut + (size_t)(blockIdx.x & (NSUB - 1)) * 8 + b * 2;
    atomicAdd(&dst[0], red[0] + red[1] + red[2] + red[3]);
    atomicAdd(&dst[1], red[4] + red[5] + red[6] + red[7]);
  }
}

// ---------------------------------------------------------------------------
extern "C" void kernel_launch(void* const* d_in, const int* in_sizes, int n_in,
                              void* d_out, int out_size, void* d_ws, size_t ws_size,
                              hipStream_t stream) {
  (void)in_sizes; (void)n_in; (void)out_size; (void)ws_size;
  const float* input = (const float*)d_in[0];
  const float* ln1_g = (const float*)d_in[1];
  const float* ln1_b = (const float*)d_in[2];
  const float* bn1_w = (const float*)d_in[3];
  const float* bn1_b = (const float*)d_in[4];
  const float* pw_w  = (const float*)d_in[5];
  const float* pw_b  = (const float*)d_in[6];
  const float* dw_w  = (const float*)d_in[7];
  const float* dw_b  = (const float*)d_in[8];
  const float* res_w = (const float*)d_in[9];
  const float* res_b = (const float*)d_in[10];
  const float* sk_w  = (const float*)d_in[11];
  const float* sk_b  = (const float*)d_in[12];
  const float* p1    = (const float*)d_in[13];
  const float* p2    = (const float*)d_in[14];
  const float* n1g   = (const float*)d_in[15];
  const float* n1b   = (const float*)d_in[16];
  const float* n2g   = (const float*)d_in[17];
  const float* n2b   = (const float*)d_in[18];
  const float* h1_p  = (const float*)d_in[19];
  const float* h1_w  = (const float*)d_in[20];
  const float* h1_b  = (const float*)d_in[21];
  const float* h2_p  = (const float*)d_in[22];
  const float* h2_w  = (const float*)d_in[23];
  const float* h2_b  = (const float*)d_in[24];

  float* out1 = (float*)d_out;
  float* out2 = out1 + 4096000;   // [4,256,4000]
  float* feat = out1 + 8192000;   // [4,128,4000]

  char* base = (char*)d_ws;
  float* OUTS  = (float*)base;                  base += (size_t)B_ * TP_ * 128 * 4;
  float* SKIP  = (float*)base;                  base += (size_t)B_ * TP_ * 128 * 4;
  float* OUT2  = (float*)base;                  base += (size_t)B_ * TP_ * 128 * 4;
  float* SKIP2 = (float*)base;                  base += (size_t)B_ * TP_ * 128 * 4;
  unsigned short* OUTbf  = (unsigned short*)base; base += (size_t)B_ * TP_ * 128 * 2;
  unsigned short* OUT2bf = (unsigned short*)base; base += (size_t)B_ * TP_ * 128 * 2;
  unsigned short* Ybuf = (unsigned short*)base; base += (size_t)8 * YSST * 2;  // 8 slots + halo
  unsigned short* Ubuf = (unsigned short*)base; base += (size_t)8 * USST * 2;  // 8 slots
  unsigned short* Xt   = (unsigned short*)base; base += (size_t)B_ * TP_ * 256 * 2;
  unsigned short* SKbf = (unsigned short*)base; base += (size_t)2 * B_ * TP_ * 128 * 2;
  unsigned short* Wpw  = (unsigned short*)base; base += (size_t)32 * 512 * 128 * 2;
  unsigned short* Wg   = (unsigned short*)base; base += (size_t)32 * 256 * 512 * 2;
  unsigned short* Wbn  = (unsigned short*)base; base += (size_t)128 * 256 * 2;
  unsigned short* Wh1  = (unsigned short*)base; base += (size_t)256 * 128 * 2;
  unsigned short* Wh2  = (unsigned short*)base; base += (size_t)256 * 128 * 2;
  float* UVu   = (float*)base;                  base += (size_t)32 * 256 * 4;
  float* UVv   = (float*)base;                  base += (size_t)32 * 256 * 4;
  float* STATS = (float*)base;

  unsigned short* YbufD = Ybuf + (size_t)YHAL * YROW;  // data base (halo before)
  const int npr = B_ * TP_ * 128;

  hipMemsetAsync(STATS, 0, (size_t)65 * SLOTW * sizeof(float), stream);
  hipMemsetAsync(SKIP, 0, (size_t)B_ * TP_ * 128 * sizeof(float), stream);

  const float invN_in = 1.0f / (256.0f * 4000.0f);
  const float invN_h  = 1.0f / (512.0f * 4000.0f);

  // weight prep
  cvt_bf<<<2048, 256, 0, stream>>>(pw_w, Wpw, 32 * 512 * 128);
  cvt_bf<<<128, 256, 0, stream>>>(bn1_w, Wbn, 128 * 256);
  cvt_bf<<<128, 256, 0, stream>>>(h1_w, Wh1, 256 * 128);
  cvt_bf<<<128, 256, 0, stream>>>(h2_w, Wh2, 256 * 128);
  fold_rs<<<32 * 256, 256, 0, stream>>>(res_w, sk_w, n2g, n2b, Wg, UVu, UVv);

  // input GN -> bf16 [t][256] -> bottleneck GEMM (K=256 -> BK=128)
  gn_stats<<<dim3(64, B_), 256, 0, stream>>>(input, STATS, 256 * T_);
  tin<<<dim3(63, 4, B_), 256, 0, stream>>>(input, Xt, ln1_g, ln1_b, STATS, invN_in);
  {
    MMP q{}; q.A0 = Wbn; q.B0 = Xt; q.bias0 = bn1_b; q.O0a = OUTS; q.Obf0 = OUTbf;
    q.K = 256;
    mm6<0, 128, 0, 128><<<dim3(32, 1, B_), 256, 0, stream>>>(q);
  }

  // ---- serial blocks 0..15 (shared trunk)
  auto pw_one = [&](int i) {
    MMP q{}; q.A0 = Wpw + (size_t)i * 512 * 128; q.B0 = OUTbf;
    q.bias0 = pw_b + (size_t)i * 512; q.Obf0 = YbufD; q.al0 = p1 + i;
    q.so0 = STATS + (size_t)(1 + 2 * i) * SLOTW; q.K = 128;
    mm6<1, 128, 0, 64><<<dim3(32, 4, B_), 256, 0, stream>>>(q);
  };
  auto dw_one = [&](int i) {
    float* sA = STATS + (size_t)(1 + 2 * i) * SLOTW;
    float* sB = STATS + (size_t)(2 + 2 * i) * SLOTW;
    dw3<<<dim3(250, B_), 256, 0, stream>>>(
        YbufD, Ubuf, dw_w + (size_t)i * 512 * 3, nullptr,
        dw_b + (size_t)i * 512, nullptr, n1g + (size_t)i * 512, nullptr,
        n1b + (size_t)i * 512, nullptr, p2 + i, nullptr, sA, nullptr, invN_h,
        sB, nullptr, 1 << (i & 7), 99);
  };
  auto rs_one = [&](int i, int flg) {
    MMP q{}; q.A0 = Wg + (size_t)i * 256 * 512; q.B0 = Ubuf;
    q.O0a = OUTS; q.O1a = SKIP; q.Obf0 = OUTbf;
    q.si0 = STATS + (size_t)(2 + 2 * i) * SLOTW; q.invN = invN_h;
    q.Uc0 = UVu + (size_t)i * 256; q.Vc0 = UVv + (size_t)i * 256;
    q.rb0 = res_b + (size_t)i * 128; q.sb0 = sk_b + (size_t)i * 128;
    q.feat = feat; q.dupO0 = OUT2; q.dupObf = OUT2bf; q.dupO1 = SKIP2;
    q.K = 512;
    if (flg == 2)      mm6<2, 64, 2, 128><<<dim3(64, 2, B_), 256, 0, stream>>>(q);
    else if (flg == 4) mm6<2, 64, 4, 128><<<dim3(64, 2, B_), 256, 0, stream>>>(q);
    else               mm6<2, 64, 0, 128><<<dim3(64, 2, B_), 256, 0, stream>>>(q);
  };

  for (int i = 0; i < 16; ++i) {
    pw_one(i);
    dw_one(i);
    rs_one(i, (i == 7) ? 2 : (i == 15) ? 4 : 0);
  }

  // ---- paired blocks: branch1 = 16+j, branch2 = 24+j
  for (int j = 0; j < 8; ++j) {
    const int i1 = 16 + j, i2 = 24 + j;
    float* sA1 = STATS + (size_t)(1 + 2 * i1) * SLOTW;
    float* sB1 = STATS + (size_t)(2 + 2 * i1) * SLOTW;
    float* sA2 = STATS + (size_t)(1 + 2 * i2) * SLOTW;
    float* sB2 = STATS + (size_t)(2 + 2 * i2) * SLOTW;
    {
      MMP q{};
      q.A0 = Wpw + (size_t)i1 * 512 * 128; q.A1 = Wpw + (size_t)i2 * 512 * 128;
      q.B0 = OUTbf; q.B1 = OUT2bf;
      q.bias0 = pw_b + (size_t)i1 * 512; q.bias1 = pw_b + (size_t)i2 * 512;
      q.Obf0 = YbufD; q.Obf1 = YbufD + 4 * YSST;
      q.al0 = p1 + i1; q.al1 = p1 + i2;
      q.so0 = sA1; q.so1 = sA2; q.K = 128;
      mm6<1, 128, 1, 64><<<dim3(32, 4, 2 * B_), 256, 0, stream>>>(q);
    }
    dw3<<<dim3(250, 2 * B_), 256, 0, stream>>>(
        YbufD, Ubuf,
        dw_w + (size_t)i1 * 512 * 3, dw_w + (size_t)i2 * 512 * 3,
        dw_b + (size_t)i1 * 512, dw_b + (size_t)i2 * 512,
        n1g + (size_t)i1 * 512, n1g + (size_t)i2 * 512,
        n1b + (size_t)i1 * 512, n1b + (size_t)i2 * 512,
        p2 + i1, p2 + i2, sA1, sA2, invN_h, sB1, sB2, 1 << (j & 7), B_);
    {
      MMP q{};
      q.A0 = Wg + (size_t)i1 * 256 * 512; q.A1 = Wg + (size_t)i2 * 256 * 512;
      q.B0 = Ubuf; q.B1 = Ubuf + 4 * USST;
      q.O0a = OUTS; q.O0b = OUT2; q.O1a = SKIP; q.O1b = SKIP2;
      q.Obf0 = OUTbf; q.Obf1 = OUT2bf;
      q.si0 = sB1; q.si1 = sB2; q.invN = invN_h;
      q.Uc0 = UVu + (size_t)i1 * 256; q.Uc1 = UVu + (size_t)i2 * 256;
      q.Vc0 = UVv + (size_t)i1 * 256; q.Vc1 = UVv + (size_t)i2 * 256;
      q.rb0 = res_b + (size_t)i1 * 128; q.rb1 = res_b + (size_t)i2 * 128;
      q.sb0 = sk_b + (size_t)i1 * 128; q.sb1 = sk_b + (size_t)i2 * 128;
      q.K = 512;
      mm6<2, 128, 1, 128><<<dim3(32, 2, 2 * B_), 256, 0, stream>>>(q);
    }
  }

  // ---- heads (both in one pass)
  prelu2<<<2048, 256, 0, stream>>>(SKIP, SKIP2, SKbf, h1_p, h2_p, npr);
  {
    MMP q{};
    q.A0 = Wh1; q.A1 = Wh2;
    q.B0 = SKbf; q.B1 = SKbf + npr;
    q.bias0 = h1_b; q.bias1 = h2_b;
    q.O0a = out1; q.O0b = out2; q.K = 128;
    mm6<3, 128, 1, 64><<<dim3(32, 2, 2 * B_), 256, 0, stream>>>(q);
  }
}

// Round 13
// 1236.459 us; speedup vs baseline: 1.0598x; 1.0059x over previous
//
#include <hip/hip_runtime.h>
#include <hip/hip_bf16.h>

// ---------------------------------------------------------------------------
// Conv-TasNet TCN, bf16-MFMA v12 = r11 verbatim (1243us verified) with the
// four cvt_bf weight-prep launches merged into one cvt4 launch (inert change).
// r12's skip-deferral (mmx) reverted: it produced an unexplained feat-local
// 0.41 error; r11 lineage is the verified-good structure.
// ---------------------------------------------------------------------------

#define T_  4000
#define TP_ 4096
#define B_  4
#define YHAL 128
#define YROW 512
#define YSST ((size_t)(TP_ + 2 * YHAL) * YROW)
#define USST ((size_t)TP_ * YROW)
#define NSUB 64
#define SLOTW (NSUB * 8)

typedef __attribute__((ext_vector_type(8))) short  s8v;
typedef __attribute__((ext_vector_type(4))) float  f32x4;
typedef __attribute__((ext_vector_type(4))) unsigned short u16x4;

__device__ __forceinline__ float bf2f(unsigned short u) {
  unsigned int i = ((unsigned int)u) << 16;
  float f; __builtin_memcpy(&f, &i, 4); return f;
}
__device__ __forceinline__ unsigned short f2bf(float f) {
  unsigned int i; __builtin_memcpy(&i, &f, 4);
  unsigned int r = i + 0x7fffu + ((i >> 16) & 1u);
  return (unsigned short)(r >> 16);
}

__device__ __forceinline__ void g2lds16(const void* g, void* l) {
  __builtin_amdgcn_global_load_lds(
      (const __attribute__((address_space(1))) unsigned int*)g,
      (__attribute__((address_space(3))) unsigned int*)l, 16, 0, 0);
}

// consumer-side: sum the 64 sub-slot partials of one stats slot (per-wave).
__device__ __forceinline__ void stats_sum(const float* __restrict__ si, int b,
                                          float& u, float& q) {
  const int lane = threadIdx.x & 63;
  u = si[lane * 8 + b * 2 + 0];
  q = si[lane * 8 + b * 2 + 1];
#pragma unroll
  for (int off = 32; off > 0; off >>= 1) {
    u += __shfl_xor(u, off);
    q += __shfl_xor(q, off);
  }
}

// ---------------- per-sample sum/sumsq over contiguous [C*T] ---------------
__global__ __launch_bounds__(256) void gn_stats(const float* __restrict__ X,
                                                float* __restrict__ statsOut, int n) {
  const int b = blockIdx.y;
  const float4* xp = (const float4*)(X + (size_t)b * n);
  const int n4 = n >> 2;
  float s1 = 0.f, s2 = 0.f;
  for (int idx = blockIdx.x * 256 + threadIdx.x; idx < n4; idx += gridDim.x * 256) {
    float4 v = xp[idx];
    s1 += v.x + v.y + v.z + v.w;
    s2 += v.x * v.x + v.y * v.y + v.z * v.z + v.w * v.w;
  }
#pragma unroll
  for (int off = 32; off > 0; off >>= 1) {
    s1 += __shfl_xor(s1, off);
    s2 += __shfl_xor(s2, off);
  }
  __shared__ float red[8];
  const int lane = threadIdx.x & 63, wv = threadIdx.x >> 6;
  if (lane == 0) { red[wv] = s1; red[4 + wv] = s2; }
  __syncthreads();
  if (threadIdx.x == 0) {
    float* dst = statsOut + (size_t)(blockIdx.x & (NSUB - 1)) * 8 + b * 2;
    atomicAdd(&dst[0], red[0] + red[1] + red[2] + red[3]);
    atomicAdd(&dst[1], red[4] + red[5] + red[6] + red[7]);
  }
}

// ---------------- weight prep: 4 fp32->bf16 conversions in one launch ------
__global__ __launch_bounds__(256) void cvt4(
    const float* __restrict__ s0, unsigned short* __restrict__ d0, int n0,
    const float* __restrict__ s1, unsigned short* __restrict__ d1, int n1,
    const float* __restrict__ s2, unsigned short* __restrict__ d2, int n2,
    const float* __restrict__ s3, unsigned short* __restrict__ d3, int n3) {
  const int total = n0 + n1 + n2 + n3;
  for (int i = blockIdx.x * 256 + threadIdx.x; i < total; i += gridDim.x * 256) {
    int j = i;
    if (j < n0) { d0[j] = f2bf(s0[j]); continue; }
    j -= n0;
    if (j < n1) { d1[j] = f2bf(s1[j]); continue; }
    j -= n1;
    if (j < n2) { d2[j] = f2bf(s2[j]); continue; }
    j -= n2;
    d3[j] = f2bf(s3[j]);
  }
}

__global__ __launch_bounds__(256) void fold_rs(
    const float* __restrict__ rw, const float* __restrict__ sw,
    const float* __restrict__ g2a, const float* __restrict__ b2a,
    unsigned short* __restrict__ Wg, float* __restrict__ Ucb,
    float* __restrict__ Vcb) {
  const int row = blockIdx.x;                 // i*256 + m
  const int i = row >> 8, m = row & 255;
  const float* src = (m < 128) ? rw + ((size_t)i * 128 + m) * 512
                               : sw + ((size_t)i * 128 + (m - 128)) * 512;
  const float* g = g2a + (size_t)i * 512;
  const float* bb = b2a + (size_t)i * 512;
  unsigned short* dst = Wg + (size_t)row * 512;
  float u = 0.f, v = 0.f;
  for (int h = threadIdx.x; h < 512; h += 256) {
    float wgt = src[h] * g[h];
    dst[h] = f2bf(wgt);
    u += wgt; v += src[h] * bb[h];
  }
#pragma unroll
  for (int off = 32; off > 0; off >>= 1) {
    u += __shfl_xor(u, off);
    v += __shfl_xor(v, off);
  }
  __shared__ float red[8];
  const int lane = threadIdx.x & 63, wv = threadIdx.x >> 6;
  if (lane == 0) { red[wv] = u; red[4 + wv] = v; }
  __syncthreads();
  if (threadIdx.x == 0) {
    Ucb[row] = red[0] + red[1] + red[2] + red[3];
    Vcb[row] = red[4] + red[5] + red[6] + red[7];
  }
}

// both heads' prelu+cvt in one launch
__global__ __launch_bounds__(256) void prelu2(const float* __restrict__ S0,
                                              const float* __restrict__ S1,
                                              unsigned short* __restrict__ D,
                                              const float* __restrict__ a0p,
                                              const float* __restrict__ a1p, int n) {
  const float a0 = a0p[0], a1 = a1p[0];
  for (int i = blockIdx.x * 256 + threadIdx.x; i < 2 * n; i += gridDim.x * 256) {
    float v = (i < n) ? S0[i] : S1[i - n];
    float a = (i < n) ? a0 : a1;
    v = v >= 0.f ? v : a * v;
    D[i] = f2bf(v);
  }
}

// ---------------- input transpose + GN affine + bf16 -----------------------
__global__ __launch_bounds__(256) void tin(const float* __restrict__ X,
                                           unsigned short* __restrict__ Xt,
                                           const float* __restrict__ g,
                                           const float* __restrict__ bt,
                                           const float* __restrict__ sIn, float invN) {
  const int b = blockIdx.z, c0 = blockIdx.y * 64, t0 = blockIdx.x * 64;
  __shared__ float tile[64][65];
  const int tid = threadIdx.x;
  float su, sq;
  stats_sum(sIn, b, su, sq);
  const float mean = su * invN;
  const float rs = rsqrtf(sq * invN - mean * mean + 1e-8f);
  {
    const int cl = tid >> 2, tq = (tid & 3) * 16;
    const float* Xr = X + ((size_t)b * 256 + c0 + cl) * T_;
#pragma unroll
    for (int j = 0; j < 4; ++j) {
      int tt = t0 + tq + j * 4;
      float4 v;
      if (tt + 3 < T_) v = *(const float4*)(Xr + tt);
      else {
        v.x = (tt + 0 < T_) ? Xr[tt + 0] : 0.f;
        v.y = (tt + 1 < T_) ? Xr[tt + 1] : 0.f;
        v.z = (tt + 2 < T_) ? Xr[tt + 2] : 0.f;
        v.w = (tt + 3 < T_) ? Xr[tt + 3] : 0.f;
      }
      tile[cl][tq + j * 4 + 0] = v.x; tile[cl][tq + j * 4 + 1] = v.y;
      tile[cl][tq + j * 4 + 2] = v.z; tile[cl][tq + j * 4 + 3] = v.w;
    }
  }
  __syncthreads();
  {
    const int tl = tid >> 2, cq = (tid & 3) * 16;
    const int t = t0 + tl;
    if (t < T_) {
      unsigned short* dst = Xt + ((size_t)b * TP_ + t) * 256 + c0 + cq;
      s8v u0, u1;
#pragma unroll
      for (int j = 0; j < 16; ++j) {
        int c = c0 + cq + j;
        float sc = rs * g[c];
        float oc = bt[c] - mean * sc;
        unsigned short uu = f2bf(tile[cq + j][tl] * sc + oc);
        if (j < 8) u0[j] = (short)uu; else u1[j - 8] = (short)uu;
      }
      *(s8v*)dst = u0;
      *(s8v*)(dst + 8) = u1;
    }
  }
}

// ---------------- mm6 params ------------------------------------------------
struct MMP {
  const unsigned short *A0, *A1, *B0, *B1;
  const float *bias0, *bias1;
  float *O0a, *O0b, *O1a, *O1b;
  unsigned short *Obf0, *Obf1;
  const float *al0, *al1;
  float *so0, *so1;
  const float *si0, *si1;
  const float *Uc0, *Uc1, *Vc0, *Vc1, *rb0, *rb1, *sb0, *sb1;
  float* feat;
  float* dupO0; unsigned short* dupObf; float* dupO1;
  int K; float invN;
};

// ---------------- clean bf16 MFMA GEMM, 128m x TNt x BKk, single-buffer ----
// BK in {64,128}; LDS holds KH=BK/64 independent 64-k planes, each staged and
// read with the identical XOR-swizzle idiom (KH=1 == r8 code exactly).
// EPI 0: O0 fp32 [t][128] = v+bias, Obf shadow                (bn1)
// EPI 1: prelu -> Obf bf16 Y-slot (halo stride YSST) + GN stats (pw)
// EPI 2: GN2-folded; y==0: res RMW O0 + shadow; y==1: skip RMW O1
//        WF: also write feat; DUP: also write fork copies
// EPI 3: masked fp32 scatter O0[b][256][4000] = v+bias         (heads)
// FLG: 1=PAIR (blockIdx.z >= gridDim.z/2 -> branch-2 pointers)
template <int EPI, int TN, int FLG, int BK>
__global__ __launch_bounds__(256) void mm6(MMP p) {
  constexpr bool PAIR = (FLG & 1) != 0;
  constexpr bool WF   = (FLG & 2) != 0;
  constexpr bool DUPF = (FLG & 4) != 0;
  constexpr int NJ = TN / 32;
  constexpr int KH = BK / 64;
  __shared__ unsigned short As[KH * 128 * 64];
  __shared__ unsigned short Bs[KH * TN * 64];
  __shared__ float redw[8];
  int b = blockIdx.z; bool br2 = false;
  if constexpr (PAIR) {
    const int h = gridDim.z >> 1;
    if (b >= h) { br2 = true; b -= h; }
  }
  const int K = p.K;
  const unsigned short* A  = br2 ? p.A1 : p.A0;
  const unsigned short* Bm = br2 ? p.B1 : p.B0;
  const int m0 = blockIdx.y * 128;
  const int t0 = blockIdx.x * TN;
  const int tid = threadIdx.x;
  const int lane = tid & 63;
  const int w = tid >> 6;
  const int wm = w >> 1, wn = w & 1;
  const int lt = lane & 15, lg = lane >> 4;
  const unsigned short* Ab = A + (size_t)m0 * K;
  const unsigned short* Bb = Bm + ((size_t)b * TP_ + t0) * K;
  const int srow8 = lane >> 3;
  const int skc   = ((lane & 7) ^ (lane >> 3)) * 8;

  f32x4 acc[4][NJ];
#pragma unroll
  for (int i = 0; i < 4; ++i)
#pragma unroll
    for (int j = 0; j < NJ; ++j) acc[i][j] = (f32x4){0.f, 0.f, 0.f, 0.f};

  for (int k0 = 0; k0 < K; k0 += BK) {
#pragma unroll
    for (int kh = 0; kh < KH; ++kh) {
#pragma unroll
      for (int c = 0; c < 4; ++c) {
        const int ch = w * 4 + c;
        g2lds16(Ab + (size_t)(ch * 8 + srow8) * K + k0 + kh * 64 + skc,
                &As[kh * 8192 + ch * 512]);
      }
#pragma unroll
      for (int c = 0; c < NJ; ++c) {
        const int ch = w * NJ + c;
        g2lds16(Bb + (size_t)(ch * 8 + srow8) * K + k0 + kh * 64 + skc,
                &Bs[kh * TN * 64 + ch * 512]);
      }
    }
    __syncthreads();
#pragma unroll
    for (int kss = 0; kss < 2 * KH; ++kss) {
      const int kh = kss >> 1, ks = kss & 1;
      s8v bfr[NJ];
#pragma unroll
      for (int j = 0; j < NJ; ++j) {
        const int R = wn * (TN / 2) + j * 16 + lt;
        bfr[j] = *(const s8v*)&Bs[kh * TN * 64 + R * 64 + (((ks * 4 + lg) ^ (R & 7)) * 8)];
      }
#pragma unroll
      for (int i = 0; i < 4; ++i) {
        const int R = wm * 64 + i * 16 + lt;
        s8v af = *(const s8v*)&As[kh * 8192 + R * 64 + (((ks * 4 + lg) ^ (R & 7)) * 8)];
#pragma unroll
        for (int j = 0; j < NJ; ++j)
          acc[i][j] = __builtin_amdgcn_mfma_f32_16x16x32_bf16(af, bfr[j], acc[i][j], 0, 0, 0);
      }
    }
    __syncthreads();
  }

  if constexpr (EPI == 0) {
    const float* bias = p.bias0;
#pragma unroll
    for (int i = 0; i < 4; ++i) {
      const int mg = m0 + wm * 64 + i * 16 + lg * 4;
      float4 bi = *(const float4*)(bias + mg);
#pragma unroll
      for (int j = 0; j < NJ; ++j) {
        const int t = t0 + wn * (TN / 2) + j * 16 + lt;
        f32x4 v = acc[i][j];
        float nv[4] = {v[0] + bi.x, v[1] + bi.y, v[2] + bi.z, v[3] + bi.w};
        *(float4*)(p.O0a + ((size_t)b * TP_ + t) * 128 + mg) =
            make_float4(nv[0], nv[1], nv[2], nv[3]);
        u16x4 pk;
#pragma unroll
        for (int r = 0; r < 4; ++r) pk[r] = f2bf(nv[r]);
        *(u16x4*)(p.Obf0 + ((size_t)b * TP_ + t) * 128 + mg) = pk;
      }
    }
  } else if constexpr (EPI == 1) {
    const float* bias = br2 ? p.bias1 : p.bias0;
    unsigned short* Obf = (br2 ? p.Obf1 : p.Obf0) + (size_t)b * YSST;
    const float aO = (br2 ? p.al1 : p.al0)[0];
    float* so = br2 ? p.so1 : p.so0;
    float s1 = 0.f, s2 = 0.f;
#pragma unroll
    for (int i = 0; i < 4; ++i) {
      const int mg = m0 + wm * 64 + i * 16 + lg * 4;
      float4 bi = *(const float4*)(bias + mg);
      float bv[4] = {bi.x, bi.y, bi.z, bi.w};
#pragma unroll
      for (int j = 0; j < NJ; ++j) {
        const int t = t0 + wn * (TN / 2) + j * 16 + lt;
        f32x4 v = acc[i][j];
        u16x4 pk;
#pragma unroll
        for (int r = 0; r < 4; ++r) {
          float f = v[r] + bv[r];
          f = f >= 0.f ? f : aO * f;
          pk[r] = f2bf(f);
        }
        *(u16x4*)(Obf + (size_t)t * YROW + mg) = pk;
        if (t < T_) {
#pragma unroll
          for (int r = 0; r < 4; ++r) { float f = bf2f(pk[r]); s1 += f; s2 += f * f; }
        }
      }
    }
#pragma unroll
    for (int off = 32; off > 0; off >>= 1) {
      s1 += __shfl_xor(s1, off);
      s2 += __shfl_xor(s2, off);
    }
    if (lane == 0) { redw[w] = s1; redw[4 + w] = s2; }
    __syncthreads();
    if (tid == 0) {
      float* dst = so + (size_t)(blockIdx.x & (NSUB - 1)) * 8 + b * 2;
      atomicAdd(&dst[0], redw[0] + redw[1] + redw[2] + redw[3]);
      atomicAdd(&dst[1], redw[4] + redw[5] + redw[6] + redw[7]);
    }
  } else if constexpr (EPI == 2) {
    float* O0 = br2 ? p.O0b : p.O0a;
    float* O1 = br2 ? p.O1b : p.O1a;
    unsigned short* Obf = br2 ? p.Obf1 : p.Obf0;
    const float* si = br2 ? p.si1 : p.si0;
    const float* Uc = br2 ? p.Uc1 : p.Uc0;
    const float* Vc = br2 ? p.Vc1 : p.Vc0;
    const float* rb = br2 ? p.rb1 : p.rb0;
    const float* sb = br2 ? p.sb1 : p.sb0;
    float su, sq;
    stats_sum(si, b, su, sq);
    const float mean = su * p.invN;
    const float rsv = rsqrtf(sq * p.invN - mean * mean + 1e-8f);
    const bool isRes = (m0 == 0);
#pragma unroll
    for (int i = 0; i < 4; ++i) {
      const int ml = wm * 64 + i * 16 + lg * 4;   // 0..127 local
      float cc[4];
#pragma unroll
      for (int r = 0; r < 4; ++r) {
        const int mgG = m0 + ml + r;
        cc[r] = Vc[mgG] - mean * rsv * Uc[mgG] + (isRes ? rb[ml + r] : sb[ml + r]);
      }
#pragma unroll
      for (int j = 0; j < NJ; ++j) {
        const int t = t0 + wn * (TN / 2) + j * 16 + lt;
        f32x4 v = acc[i][j];
        if (isRes) {
          float* ptr = O0 + ((size_t)b * TP_ + t) * 128 + ml;
          float4 old = *(float4*)ptr;
          float nv[4] = {old.x + rsv * v[0] + cc[0], old.y + rsv * v[1] + cc[1],
                         old.z + rsv * v[2] + cc[2], old.w + rsv * v[3] + cc[3]};
          *(float4*)ptr = make_float4(nv[0], nv[1], nv[2], nv[3]);
          u16x4 pk;
#pragma unroll
          for (int r = 0; r < 4; ++r) pk[r] = f2bf(nv[r]);
          *(u16x4*)(Obf + ((size_t)b * TP_ + t) * 128 + ml) = pk;
          if constexpr (DUPF) {
            *(float4*)(p.dupO0 + ((size_t)b * TP_ + t) * 128 + ml) =
                make_float4(nv[0], nv[1], nv[2], nv[3]);
            *(u16x4*)(p.dupObf + ((size_t)b * TP_ + t) * 128 + ml) = pk;
          }
          if constexpr (WF) {
            if (t < T_) {
#pragma unroll
              for (int r = 0; r < 4; ++r)
                p.feat[((size_t)b * 128 + ml + r) * T_ + t] = nv[r];
            }
          }
        } else {
          float* ptr = O1 + ((size_t)b * TP_ + t) * 128 + ml;
          float4 old = *(float4*)ptr;
          float nv[4] = {old.x + rsv * v[0] + cc[0], old.y + rsv * v[1] + cc[1],
                         old.z + rsv * v[2] + cc[2], old.w + rsv * v[3] + cc[3]};
          *(float4*)ptr = make_float4(nv[0], nv[1], nv[2], nv[3]);
          if constexpr (DUPF) {
            *(float4*)(p.dupO1 + ((size_t)b * TP_ + t) * 128 + ml) =
                make_float4(nv[0], nv[1], nv[2], nv[3]);
          }
        }
      }
    }
  } else {  // EPI 3: heads scatter to [b][256][4000]
    float* O0 = br2 ? p.O0b : p.O0a;
    const float* bias = br2 ? p.bias1 : p.bias0;
#pragma unroll
    for (int i = 0; i < 4; ++i) {
      const int mg = m0 + wm * 64 + i * 16 + lg * 4;
#pragma unroll
      for (int j = 0; j < NJ; ++j) {
        const int t = t0 + wn * (TN / 2) + j * 16 + lt;
        if (t < T_) {
          f32x4 v = acc[i][j];
#pragma unroll
          for (int r = 0; r < 4; ++r)
            O0[((size_t)b * 256 + mg + r) * T_ + t] = v[r] + bias[mg + r];
        }
      }
    }
  }
}

// ---------------- depthwise dilated conv, [t][h], unconditional loads ------
__global__ __launch_bounds__(256) void dw3(
    const unsigned short* __restrict__ Y, unsigned short* __restrict__ U,
    const float* __restrict__ dww0, const float* __restrict__ dww1,
    const float* __restrict__ dwb0, const float* __restrict__ dwb1,
    const float* __restrict__ g10, const float* __restrict__ g11,
    const float* __restrict__ b10, const float* __restrict__ b11,
    const float* __restrict__ p20, const float* __restrict__ p21,
    const float* __restrict__ sIn0, const float* __restrict__ sIn1, float invN,
    float* __restrict__ sOut0, float* __restrict__ sOut1, int dil, int halfY) {
  const int q = blockIdx.y;
  const bool br2 = q >= halfY;
  const int b = br2 ? q - halfY : q;
  const float* dww = br2 ? dww1 : dww0;
  const float* dwb = br2 ? dwb1 : dwb0;
  const float* g1  = br2 ? g11 : g10;
  const float* b1  = br2 ? b11 : b10;
  const float* p2p = br2 ? p21 : p20;
  const float* sIn = br2 ? sIn1 : sIn0;
  float* sOut      = br2 ? sOut1 : sOut0;
  const int tid = threadIdx.x;
  const int hc = (tid & 63) * 8;
  const int tbase = blockIdx.x * 16 + (tid >> 6) * 4;

  float su, sq2;
  stats_sum(sIn, b, su, sq2);
  const float mean = su * invN;
  const float rs = rsqrtf(sq2 * invN - mean * mean + 1e-8f);
  float sA[8], oA[8], w0[8], w1[8], w2[8], bb[8];
#pragma unroll
  for (int j = 0; j < 8; ++j) {
    sA[j] = rs * g1[hc + j];
    oA[j] = b1[hc + j] - mean * sA[j];
    w0[j] = dww[(hc + j) * 3 + 0];
    w1[j] = dww[(hc + j) * 3 + 1];
    w2[j] = dww[(hc + j) * 3 + 2];
    bb[j] = dwb[hc + j];
  }
  const float alpha = p2p[0];
  const unsigned short* Yb = Y + (size_t)q * YSST;
  unsigned short* Ub = U + (size_t)q * USST;

  s8v xm[4], x0[4], xp[4];
#pragma unroll
  for (int i = 0; i < 4; ++i) {
    const int t = tbase + i;
    xm[i] = *(const s8v*)(Yb + (size_t)(t - dil) * YROW + hc);
    x0[i] = *(const s8v*)(Yb + (size_t)t * YROW + hc);
    xp[i] = *(const s8v*)(Yb + (size_t)(t + dil) * YROW + hc);
  }

  float s1 = 0.f, s2 = 0.f;
#pragma unroll
  for (int i = 0; i < 4; ++i) {
    const int t = tbase + i;
    const bool vm = (t - dil >= 0), vp = (t + dil < T_);
    s8v out;
#pragma unroll
    for (int j = 0; j < 8; ++j) {
      float fm = vm ? (bf2f((unsigned short)xm[i][j]) * sA[j] + oA[j]) : 0.f;
      float f0 = bf2f((unsigned short)x0[i][j]) * sA[j] + oA[j];
      float fp = vp ? (bf2f((unsigned short)xp[i][j]) * sA[j] + oA[j]) : 0.f;
      float v = fmaf(w0[j], fm, fmaf(w1[j], f0, fmaf(w2[j], fp, bb[j])));
      v = v >= 0.f ? v : alpha * v;
      unsigned short u = f2bf(v);
      out[j] = (short)u;
      float f = bf2f(u);
      s1 += f; s2 += f * f;
    }
    *(s8v*)(Ub + (size_t)t * YROW + hc) = out;
  }
#pragma unroll
  for (int off = 32; off > 0; off >>= 1) {
    s1 += __shfl_xor(s1, off);
    s2 += __shfl_xor(s2, off);
  }
  __shared__ float red[8];
  const int lane = tid & 63, wv = tid >> 6;
  if (lane == 0) { red[wv] = s1; red[4 + wv] = s2; }
  __syncthreads();
  if (tid == 0) {
    float* dst = sOut + (size_t)(blockIdx.x & (NSUB - 1)) * 8 + b * 2;
    atomicAdd(&dst[0], red[0] + red[1] + red[2] + red[3]);
    atomicAdd(&dst[1], red[4] + red[5] + red[6] + red[7]);
  }
}

// ---------------------------------------------------------------------------
extern "C" void kernel_launch(void* const* d_in, const int* in_sizes, int n_in,
                              void* d_out, int out_size, void* d_ws, size_t ws_size,
                              hipStream_t stream) {
  (void)in_sizes; (void)n_in; (void)out_size; (void)ws_size;
  const float* input = (const float*)d_in[0];
  const float* ln1_g = (const float*)d_in[1];
  const float* ln1_b = (const float*)d_in[2];
  const float* bn1_w = (const float*)d_in[3];
  const float* bn1_b = (const float*)d_in[4];
  const float* pw_w  = (const float*)d_in[5];
  const float* pw_b  = (const float*)d_in[6];
  const float* dw_w  = (const float*)d_in[7];
  const float* dw_b  = (const float*)d_in[8];
  const float* res_w = (const float*)d_in[9];
  const float* res_b = (const float*)d_in[10];
  const float* sk_w  = (const float*)d_in[11];
  const float* sk_b  = (const float*)d_in[12];
  const float* p1    = (const float*)d_in[13];
  const float* p2    = (const float*)d_in[14];
  const float* n1g   = (const float*)d_in[15];
  const float* n1b   = (const float*)d_in[16];
  const float* n2g   = (const float*)d_in[17];
  const float* n2b   = (const float*)d_in[18];
  const float* h1_p  = (const float*)d_in[19];
  const float* h1_w  = (const float*)d_in[20];
  const float* h1_b  = (const float*)d_in[21];
  const float* h2_p  = (const float*)d_in[22];
  const float* h2_w  = (const float*)d_in[23];
  const float* h2_b  = (const float*)d_in[24];

  float* out1 = (float*)d_out;
  float* out2 = out1 + 4096000;   // [4,256,4000]
  float* feat = out1 + 8192000;   // [4,128,4000]

  char* base = (char*)d_ws;
  float* OUTS  = (float*)base;                  base += (size_t)B_ * TP_ * 128 * 4;
  float* SKIP  = (float*)base;                  base += (size_t)B_ * TP_ * 128 * 4;
  float* OUT2  = (float*)base;                  base += (size_t)B_ * TP_ * 128 * 4;
  float* SKIP2 = (float*)base;                  base += (size_t)B_ * TP_ * 128 * 4;
  unsigned short* OUTbf  = (unsigned short*)base; base += (size_t)B_ * TP_ * 128 * 2;
  unsigned short* OUT2bf = (unsigned short*)base; base += (size_t)B_ * TP_ * 128 * 2;
  unsigned short* Ybuf = (unsigned short*)base; base += (size_t)8 * YSST * 2;  // 8 slots + halo
  unsigned short* Ubuf = (unsigned short*)base; base += (size_t)8 * USST * 2;  // 8 slots
  unsigned short* Xt   = (unsigned short*)base; base += (size_t)B_ * TP_ * 256 * 2;
  unsigned short* SKbf = (unsigned short*)base; base += (size_t)2 * B_ * TP_ * 128 * 2;
  unsigned short* Wpw  = (unsigned short*)base; base += (size_t)32 * 512 * 128 * 2;
  unsigned short* Wg   = (unsigned short*)base; base += (size_t)32 * 256 * 512 * 2;
  unsigned short* Wbn  = (unsigned short*)base; base += (size_t)128 * 256 * 2;
  unsigned short* Wh1  = (unsigned short*)base; base += (size_t)256 * 128 * 2;
  unsigned short* Wh2  = (unsigned short*)base; base += (size_t)256 * 128 * 2;
  float* UVu   = (float*)base;                  base += (size_t)32 * 256 * 4;
  float* UVv   = (float*)base;                  base += (size_t)32 * 256 * 4;
  float* STATS = (float*)base;

  unsigned short* YbufD = Ybuf + (size_t)YHAL * YROW;  // data base (halo before)
  const int npr = B_ * TP_ * 128;

  hipMemsetAsync(STATS, 0, (size_t)65 * SLOTW * sizeof(float), stream);
  hipMemsetAsync(SKIP, 0, (size_t)B_ * TP_ * 128 * sizeof(float), stream);

  const float invN_in = 1.0f / (256.0f * 4000.0f);
  const float invN_h  = 1.0f / (512.0f * 4000.0f);

  // weight prep (one merged cvt launch + fold)
  cvt4<<<2048, 256, 0, stream>>>(pw_w, Wpw, 32 * 512 * 128,
                                 bn1_w, Wbn, 128 * 256,
                                 h1_w, Wh1, 256 * 128,
                                 h2_w, Wh2, 256 * 128);
  fold_rs<<<32 * 256, 256, 0, stream>>>(res_w, sk_w, n2g, n2b, Wg, UVu, UVv);

  // input GN -> bf16 [t][256] -> bottleneck GEMM (K=256 -> BK=128)
  gn_stats<<<dim3(64, B_), 256, 0, stream>>>(input, STATS, 256 * T_);
  tin<<<dim3(63, 4, B_), 256, 0, stream>>>(input, Xt, ln1_g, ln1_b, STATS, invN_in);
  {
    MMP q{}; q.A0 = Wbn; q.B0 = Xt; q.bias0 = bn1_b; q.O0a = OUTS; q.Obf0 = OUTbf;
    q.K = 256;
    mm6<0, 128, 0, 128><<<dim3(32, 1, B_), 256, 0, stream>>>(q);
  }

  // ---- serial blocks 0..15 (shared trunk)
  auto pw_one = [&](int i) {
    MMP q{}; q.A0 = Wpw + (size_t)i * 512 * 128; q.B0 = OUTbf;
    q.bias0 = pw_b + (size_t)i * 512; q.Obf0 = YbufD; q.al0 = p1 + i;
    q.so0 = STATS + (size_t)(1 + 2 * i) * SLOTW; q.K = 128;
    mm6<1, 128, 0, 64><<<dim3(32, 4, B_), 256, 0, stream>>>(q);
  };
  auto dw_one = [&](int i) {
    float* sA = STATS + (size_t)(1 + 2 * i) * SLOTW;
    float* sB = STATS + (size_t)(2 + 2 * i) * SLOTW;
    dw3<<<dim3(250, B_), 256, 0, stream>>>(
        YbufD, Ubuf, dw_w + (size_t)i * 512 * 3, nullptr,
        dw_b + (size_t)i * 512, nullptr, n1g + (size_t)i * 512, nullptr,
        n1b + (size_t)i * 512, nullptr, p2 + i, nullptr, sA, nullptr, invN_h,
        sB, nullptr, 1 << (i & 7), 99);
  };
  auto rs_one = [&](int i, int flg) {
    MMP q{}; q.A0 = Wg + (size_t)i * 256 * 512; q.B0 = Ubuf;
    q.O0a = OUTS; q.O1a = SKIP; q.Obf0 = OUTbf;
    q.si0 = STATS + (size_t)(2 + 2 * i) * SLOTW; q.invN = invN_h;
    q.Uc0 = UVu + (size_t)i * 256; q.Vc0 = UVv + (size_t)i * 256;
    q.rb0 = res_b + (size_t)i * 128; q.sb0 = sk_b + (size_t)i * 128;
    q.feat = feat; q.dupO0 = OUT2; q.dupObf = OUT2bf; q.dupO1 = SKIP2;
    q.K = 512;
    if (flg == 2)      mm6<2, 64, 2, 128><<<dim3(64, 2, B_), 256, 0, stream>>>(q);
    else if (flg == 4) mm6<2, 64, 4, 128><<<dim3(64, 2, B_), 256, 0, stream>>>(q);
    else               mm6<2, 64, 0, 128><<<dim3(64, 2, B_), 256, 0, stream>>>(q);
  };

  for (int i = 0; i < 16; ++i) {
    pw_one(i);
    dw_one(i);
    rs_one(i, (i == 7) ? 2 : (i == 15) ? 4 : 0);
  }

  // ---- paired blocks: branch1 = 16+j, branch2 = 24+j
  for (int j = 0; j < 8; ++j) {
    const int i1 = 16 + j, i2 = 24 + j;
    float* sA1 = STATS + (size_t)(1 + 2 * i1) * SLOTW;
    float* sB1 = STATS + (size_t)(2 + 2 * i1) * SLOTW;
    float* sA2 = STATS + (size_t)(1 + 2 * i2) * SLOTW;
    float* sB2 = STATS + (size_t)(2 + 2 * i2) * SLOTW;
    {
      MMP q{};
      q.A0 = Wpw + (size_t)i1 * 512 * 128; q.A1 = Wpw + (size_t)i2 * 512 * 128;
      q.B0 = OUTbf; q.B1 = OUT2bf;
      q.bias0 = pw_b + (size_t)i1 * 512; q.bias1 = pw_b + (size_t)i2 * 512;
      q.Obf0 = YbufD; q.Obf1 = YbufD + 4 * YSST;
      q.al0 = p1 + i1; q.al1 = p1 + i2;
      q.so0 = sA1; q.so1 = sA2; q.K = 128;
      mm6<1, 128, 1, 64><<<dim3(32, 4, 2 * B_), 256, 0, stream>>>(q);
    }
    dw3<<<dim3(250, 2 * B_), 256, 0, stream>>>(
        YbufD, Ubuf,
        dw_w + (size_t)i1 * 512 * 3, dw_w + (size_t)i2 * 512 * 3,
        dw_b + (size_t)i1 * 512, dw_b + (size_t)i2 * 512,
        n1g + (size_t)i1 * 512, n1g + (size_t)i2 * 512,
        n1b + (size_t)i1 * 512, n1b + (size_t)i2 * 512,
        p2 + i1, p2 + i2, sA1, sA2, invN_h, sB1, sB2, 1 << (j & 7), B_);
    {
      MMP q{};
      q.A0 = Wg + (size_t)i1 * 256 * 512; q.A1 = Wg + (size_t)i2 * 256 * 512;
      q.B0 = Ubuf; q.B1 = Ubuf + 4 * USST;
      q.O0a = OUTS; q.O0b = OUT2; q.O1a = SKIP; q.O1b = SKIP2;
      q.Obf0 = OUTbf; q.Obf1 = OUT2bf;
      q.si0 = sB1; q.si1 = sB2; q.invN = invN_h;
      q.Uc0 = UVu + (size_t)i1 * 256; q.Uc1 = UVu + (size_t)i2 * 256;
      q.Vc0 = UVv + (size_t)i1 * 256; q.Vc1 = UVv + (size_t)i2 * 256;
      q.rb0 = res_b + (size_t)i1 * 128; q.rb1 = res_b + (size_t)i2 * 128;
      q.sb0 = sk_b + (size_t)i1 * 128; q.sb1 = sk_b + (size_t)i2 * 128;
      q.K = 512;
      mm6<2, 128, 1, 128><<<dim3(32, 2, 2 * B_), 256, 0, stream>>>(q);
    }
  }

  // ---- heads (both in one pass)
  prelu2<<<2048, 256, 0, stream>>>(SKIP, SKIP2, SKbf, h1_p, h2_p, npr);
  {
    MMP q{};
    q.A0 = Wh1; q.A1 = Wh2;
    q.B0 = SKbf; q.B1 = SKbf + npr;
    q.bias0 = h1_b; q.bias1 = h2_b;
    q.O0a = out1; q.O0b = out2; q.K = 128;
    mm6<3, 128, 1, 64><<<dim3(32, 2, 2 * B_), 256, 0, stream>>>(q);
  }
}

// Round 14
// 1226.045 us; speedup vs baseline: 1.0688x; 1.0085x over previous
//
#include <hip/hip_runtime.h>
#include <hip/hip_bf16.h>

// ---------------------------------------------------------------------------
// Conv-TasNet TCN, bf16-MFMA v13 = r13 (1236us verified) + three inert
// launch eliminations:
//   (1) layer-0 skip WRITE (INIT flag) -> drop SKIP memset
//   (2) heads prelu+cvt folded into j=7 paired-rs skip epilogue (SKB flag)
//       -> drop prelu2 launch
//   (3) bn1 TN=64 -> 256 blocks (was 128 = 0.5/CU)
// Same mm6 core, same sync structure, same math.
// ---------------------------------------------------------------------------

#define T_  4000
#define TP_ 4096
#define B_  4
#define YHAL 128
#define YROW 512
#define YSST ((size_t)(TP_ + 2 * YHAL) * YROW)
#define USST ((size_t)TP_ * YROW)
#define NSUB 64
#define SLOTW (NSUB * 8)

typedef __attribute__((ext_vector_type(8))) short  s8v;
typedef __attribute__((ext_vector_type(4))) float  f32x4;
typedef __attribute__((ext_vector_type(4))) unsigned short u16x4;

__device__ __forceinline__ float bf2f(unsigned short u) {
  unsigned int i = ((unsigned int)u) << 16;
  float f; __builtin_memcpy(&f, &i, 4); return f;
}
__device__ __forceinline__ unsigned short f2bf(float f) {
  unsigned int i; __builtin_memcpy(&i, &f, 4);
  unsigned int r = i + 0x7fffu + ((i >> 16) & 1u);
  return (unsigned short)(r >> 16);
}

__device__ __forceinline__ void g2lds16(const void* g, void* l) {
  __builtin_amdgcn_global_load_lds(
      (const __attribute__((address_space(1))) unsigned int*)g,
      (__attribute__((address_space(3))) unsigned int*)l, 16, 0, 0);
}

// consumer-side: sum the 64 sub-slot partials of one stats slot (per-wave).
__device__ __forceinline__ void stats_sum(const float* __restrict__ si, int b,
                                          float& u, float& q) {
  const int lane = threadIdx.x & 63;
  u = si[lane * 8 + b * 2 + 0];
  q = si[lane * 8 + b * 2 + 1];
#pragma unroll
  for (int off = 32; off > 0; off >>= 1) {
    u += __shfl_xor(u, off);
    q += __shfl_xor(q, off);
  }
}

// ---------------- per-sample sum/sumsq over contiguous [C*T] ---------------
__global__ __launch_bounds__(256) void gn_stats(const float* __restrict__ X,
                                                float* __restrict__ statsOut, int n) {
  const int b = blockIdx.y;
  const float4* xp = (const float4*)(X + (size_t)b * n);
  const int n4 = n >> 2;
  float s1 = 0.f, s2 = 0.f;
  for (int idx = blockIdx.x * 256 + threadIdx.x; idx < n4; idx += gridDim.x * 256) {
    float4 v = xp[idx];
    s1 += v.x + v.y + v.z + v.w;
    s2 += v.x * v.x + v.y * v.y + v.z * v.z + v.w * v.w;
  }
#pragma unroll
  for (int off = 32; off > 0; off >>= 1) {
    s1 += __shfl_xor(s1, off);
    s2 += __shfl_xor(s2, off);
  }
  __shared__ float red[8];
  const int lane = threadIdx.x & 63, wv = threadIdx.x >> 6;
  if (lane == 0) { red[wv] = s1; red[4 + wv] = s2; }
  __syncthreads();
  if (threadIdx.x == 0) {
    float* dst = statsOut + (size_t)(blockIdx.x & (NSUB - 1)) * 8 + b * 2;
    atomicAdd(&dst[0], red[0] + red[1] + red[2] + red[3]);
    atomicAdd(&dst[1], red[4] + red[5] + red[6] + red[7]);
  }
}

// ---------------- weight prep: 4 fp32->bf16 conversions in one launch ------
__global__ __launch_bounds__(256) void cvt4(
    const float* __restrict__ s0, unsigned short* __restrict__ d0, int n0,
    const float* __restrict__ s1, unsigned short* __restrict__ d1, int n1,
    const float* __restrict__ s2, unsigned short* __restrict__ d2, int n2,
    const float* __restrict__ s3, unsigned short* __restrict__ d3, int n3) {
  const int total = n0 + n1 + n2 + n3;
  for (int i = blockIdx.x * 256 + threadIdx.x; i < total; i += gridDim.x * 256) {
    int j = i;
    if (j < n0) { d0[j] = f2bf(s0[j]); continue; }
    j -= n0;
    if (j < n1) { d1[j] = f2bf(s1[j]); continue; }
    j -= n1;
    if (j < n2) { d2[j] = f2bf(s2[j]); continue; }
    j -= n2;
    d3[j] = f2bf(s3[j]);
  }
}

__global__ __launch_bounds__(256) void fold_rs(
    const float* __restrict__ rw, const float* __restrict__ sw,
    const float* __restrict__ g2a, const float* __restrict__ b2a,
    unsigned short* __restrict__ Wg, float* __restrict__ Ucb,
    float* __restrict__ Vcb) {
  const int row = blockIdx.x;                 // i*256 + m
  const int i = row >> 8, m = row & 255;
  const float* src = (m < 128) ? rw + ((size_t)i * 128 + m) * 512
                               : sw + ((size_t)i * 128 + (m - 128)) * 512;
  const float* g = g2a + (size_t)i * 512;
  const float* bb = b2a + (size_t)i * 512;
  unsigned short* dst = Wg + (size_t)row * 512;
  float u = 0.f, v = 0.f;
  for (int h = threadIdx.x; h < 512; h += 256) {
    float wgt = src[h] * g[h];
    dst[h] = f2bf(wgt);
    u += wgt; v += src[h] * bb[h];
  }
#pragma unroll
  for (int off = 32; off > 0; off >>= 1) {
    u += __shfl_xor(u, off);
    v += __shfl_xor(v, off);
  }
  __shared__ float red[8];
  const int lane = threadIdx.x & 63, wv = threadIdx.x >> 6;
  if (lane == 0) { red[wv] = u; red[4 + wv] = v; }
  __syncthreads();
  if (threadIdx.x == 0) {
    Ucb[row] = red[0] + red[1] + red[2] + red[3];
    Vcb[row] = red[4] + red[5] + red[6] + red[7];
  }
}

// ---------------- input transpose + GN affine + bf16 -----------------------
__global__ __launch_bounds__(256) void tin(const float* __restrict__ X,
                                           unsigned short* __restrict__ Xt,
                                           const float* __restrict__ g,
                                           const float* __restrict__ bt,
                                           const float* __restrict__ sIn, float invN) {
  const int b = blockIdx.z, c0 = blockIdx.y * 64, t0 = blockIdx.x * 64;
  __shared__ float tile[64][65];
  const int tid = threadIdx.x;
  float su, sq;
  stats_sum(sIn, b, su, sq);
  const float mean = su * invN;
  const float rs = rsqrtf(sq * invN - mean * mean + 1e-8f);
  {
    const int cl = tid >> 2, tq = (tid & 3) * 16;
    const float* Xr = X + ((size_t)b * 256 + c0 + cl) * T_;
#pragma unroll
    for (int j = 0; j < 4; ++j) {
      int tt = t0 + tq + j * 4;
      float4 v;
      if (tt + 3 < T_) v = *(const float4*)(Xr + tt);
      else {
        v.x = (tt + 0 < T_) ? Xr[tt + 0] : 0.f;
        v.y = (tt + 1 < T_) ? Xr[tt + 1] : 0.f;
        v.z = (tt + 2 < T_) ? Xr[tt + 2] : 0.f;
        v.w = (tt + 3 < T_) ? Xr[tt + 3] : 0.f;
      }
      tile[cl][tq + j * 4 + 0] = v.x; tile[cl][tq + j * 4 + 1] = v.y;
      tile[cl][tq + j * 4 + 2] = v.z; tile[cl][tq + j * 4 + 3] = v.w;
    }
  }
  __syncthreads();
  {
    const int tl = tid >> 2, cq = (tid & 3) * 16;
    const int t = t0 + tl;
    if (t < T_) {
      unsigned short* dst = Xt + ((size_t)b * TP_ + t) * 256 + c0 + cq;
      s8v u0, u1;
#pragma unroll
      for (int j = 0; j < 16; ++j) {
        int c = c0 + cq + j;
        float sc = rs * g[c];
        float oc = bt[c] - mean * sc;
        unsigned short uu = f2bf(tile[cq + j][tl] * sc + oc);
        if (j < 8) u0[j] = (short)uu; else u1[j - 8] = (short)uu;
      }
      *(s8v*)dst = u0;
      *(s8v*)(dst + 8) = u1;
    }
  }
}

// ---------------- mm6 params ------------------------------------------------
struct MMP {
  const unsigned short *A0, *A1, *B0, *B1;
  const float *bias0, *bias1;
  float *O0a, *O0b, *O1a, *O1b;
  unsigned short *Obf0, *Obf1;
  const float *al0, *al1;
  float *so0, *so1;
  const float *si0, *si1;
  const float *Uc0, *Uc1, *Vc0, *Vc1, *rb0, *rb1, *sb0, *sb1;
  float* feat;
  float* dupO0; unsigned short* dupObf; float* dupO1;
  unsigned short *skb0, *skb1;
  int K; float invN;
};

// ---------------- clean bf16 MFMA GEMM, 128m x TNt x BKk, single-buffer ----
// EPI 0: O0 fp32 [t][128] = v+bias, Obf shadow                (bn1)
// EPI 1: prelu -> Obf bf16 Y-slot (halo stride YSST) + GN stats (pw)
// EPI 2: GN2-folded; y==0: res RMW O0 + shadow; y==1: skip RMW O1
//        WF: also feat; DUP: fork copies; INIT: skip WRITE (no RMW);
//        SKB: skip also emits f2bf(prelu(nv)) to skb (heads input)
// EPI 3: masked fp32 scatter O0[b][256][4000] = v+bias         (heads)
// FLG bits: 1=PAIR 2=WF 4=DUP 8=INIT 16=SKB
template <int EPI, int TN, int FLG, int BK>
__global__ __launch_bounds__(256) void mm6(MMP p) {
  constexpr bool PAIR  = (FLG & 1) != 0;
  constexpr bool WF    = (FLG & 2) != 0;
  constexpr bool DUPF  = (FLG & 4) != 0;
  constexpr bool INITF = (FLG & 8) != 0;
  constexpr bool SKBF  = (FLG & 16) != 0;
  constexpr int NJ = TN / 32;
  constexpr int KH = BK / 64;
  __shared__ unsigned short As[KH * 128 * 64];
  __shared__ unsigned short Bs[KH * TN * 64];
  __shared__ float redw[8];
  int b = blockIdx.z; bool br2 = false;
  if constexpr (PAIR) {
    const int h = gridDim.z >> 1;
    if (b >= h) { br2 = true; b -= h; }
  }
  const int K = p.K;
  const unsigned short* A  = br2 ? p.A1 : p.A0;
  const unsigned short* Bm = br2 ? p.B1 : p.B0;
  const int m0 = blockIdx.y * 128;
  const int t0 = blockIdx.x * TN;
  const int tid = threadIdx.x;
  const int lane = tid & 63;
  const int w = tid >> 6;
  const int wm = w >> 1, wn = w & 1;
  const int lt = lane & 15, lg = lane >> 4;
  const unsigned short* Ab = A + (size_t)m0 * K;
  const unsigned short* Bb = Bm + ((size_t)b * TP_ + t0) * K;
  const int srow8 = lane >> 3;
  const int skc   = ((lane & 7) ^ (lane >> 3)) * 8;

  f32x4 acc[4][NJ];
#pragma unroll
  for (int i = 0; i < 4; ++i)
#pragma unroll
    for (int j = 0; j < NJ; ++j) acc[i][j] = (f32x4){0.f, 0.f, 0.f, 0.f};

  for (int k0 = 0; k0 < K; k0 += BK) {
#pragma unroll
    for (int kh = 0; kh < KH; ++kh) {
#pragma unroll
      for (int c = 0; c < 4; ++c) {
        const int ch = w * 4 + c;
        g2lds16(Ab + (size_t)(ch * 8 + srow8) * K + k0 + kh * 64 + skc,
                &As[kh * 8192 + ch * 512]);
      }
#pragma unroll
      for (int c = 0; c < NJ; ++c) {
        const int ch = w * NJ + c;
        g2lds16(Bb + (size_t)(ch * 8 + srow8) * K + k0 + kh * 64 + skc,
                &Bs[kh * TN * 64 + ch * 512]);
      }
    }
    __syncthreads();
#pragma unroll
    for (int kss = 0; kss < 2 * KH; ++kss) {
      const int kh = kss >> 1, ks = kss & 1;
      s8v bfr[NJ];
#pragma unroll
      for (int j = 0; j < NJ; ++j) {
        const int R = wn * (TN / 2) + j * 16 + lt;
        bfr[j] = *(const s8v*)&Bs[kh * TN * 64 + R * 64 + (((ks * 4 + lg) ^ (R & 7)) * 8)];
      }
#pragma unroll
      for (int i = 0; i < 4; ++i) {
        const int R = wm * 64 + i * 16 + lt;
        s8v af = *(const s8v*)&As[kh * 8192 + R * 64 + (((ks * 4 + lg) ^ (R & 7)) * 8)];
#pragma unroll
        for (int j = 0; j < NJ; ++j)
          acc[i][j] = __builtin_amdgcn_mfma_f32_16x16x32_bf16(af, bfr[j], acc[i][j], 0, 0, 0);
      }
    }
    __syncthreads();
  }

  if constexpr (EPI == 0) {
    const float* bias = p.bias0;
#pragma unroll
    for (int i = 0; i < 4; ++i) {
      const int mg = m0 + wm * 64 + i * 16 + lg * 4;
      float4 bi = *(const float4*)(bias + mg);
#pragma unroll
      for (int j = 0; j < NJ; ++j) {
        const int t = t0 + wn * (TN / 2) + j * 16 + lt;
        f32x4 v = acc[i][j];
        float nv[4] = {v[0] + bi.x, v[1] + bi.y, v[2] + bi.z, v[3] + bi.w};
        *(float4*)(p.O0a + ((size_t)b * TP_ + t) * 128 + mg) =
            make_float4(nv[0], nv[1], nv[2], nv[3]);
        u16x4 pk;
#pragma unroll
        for (int r = 0; r < 4; ++r) pk[r] = f2bf(nv[r]);
        *(u16x4*)(p.Obf0 + ((size_t)b * TP_ + t) * 128 + mg) = pk;
      }
    }
  } else if constexpr (EPI == 1) {
    const float* bias = br2 ? p.bias1 : p.bias0;
    unsigned short* Obf = (br2 ? p.Obf1 : p.Obf0) + (size_t)b * YSST;
    const float aO = (br2 ? p.al1 : p.al0)[0];
    float* so = br2 ? p.so1 : p.so0;
    float s1 = 0.f, s2 = 0.f;
#pragma unroll
    for (int i = 0; i < 4; ++i) {
      const int mg = m0 + wm * 64 + i * 16 + lg * 4;
      float4 bi = *(const float4*)(bias + mg);
      float bv[4] = {bi.x, bi.y, bi.z, bi.w};
#pragma unroll
      for (int j = 0; j < NJ; ++j) {
        const int t = t0 + wn * (TN / 2) + j * 16 + lt;
        f32x4 v = acc[i][j];
        u16x4 pk;
#pragma unroll
        for (int r = 0; r < 4; ++r) {
          float f = v[r] + bv[r];
          f = f >= 0.f ? f : aO * f;
          pk[r] = f2bf(f);
        }
        *(u16x4*)(Obf + (size_t)t * YROW + mg) = pk;
        if (t < T_) {
#pragma unroll
          for (int r = 0; r < 4; ++r) { float f = bf2f(pk[r]); s1 += f; s2 += f * f; }
        }
      }
    }
#pragma unroll
    for (int off = 32; off > 0; off >>= 1) {
      s1 += __shfl_xor(s1, off);
      s2 += __shfl_xor(s2, off);
    }
    if (lane == 0) { redw[w] = s1; redw[4 + w] = s2; }
    __syncthreads();
    if (tid == 0) {
      float* dst = so + (size_t)(blockIdx.x & (NSUB - 1)) * 8 + b * 2;
      atomicAdd(&dst[0], redw[0] + redw[1] + redw[2] + redw[3]);
      atomicAdd(&dst[1], redw[4] + redw[5] + redw[6] + redw[7]);
    }
  } else if constexpr (EPI == 2) {
    float* O0 = br2 ? p.O0b : p.O0a;
    float* O1 = br2 ? p.O1b : p.O1a;
    unsigned short* Obf = br2 ? p.Obf1 : p.Obf0;
    const float* si = br2 ? p.si1 : p.si0;
    const float* Uc = br2 ? p.Uc1 : p.Uc0;
    const float* Vc = br2 ? p.Vc1 : p.Vc0;
    const float* rb = br2 ? p.rb1 : p.rb0;
    const float* sb = br2 ? p.sb1 : p.sb0;
    float su, sq;
    stats_sum(si, b, su, sq);
    const float mean = su * p.invN;
    const float rsv = rsqrtf(sq * p.invN - mean * mean + 1e-8f);
    const bool isRes = (m0 == 0);
#pragma unroll
    for (int i = 0; i < 4; ++i) {
      const int ml = wm * 64 + i * 16 + lg * 4;   // 0..127 local
      float cc[4];
#pragma unroll
      for (int r = 0; r < 4; ++r) {
        const int mgG = m0 + ml + r;
        cc[r] = Vc[mgG] - mean * rsv * Uc[mgG] + (isRes ? rb[ml + r] : sb[ml + r]);
      }
#pragma unroll
      for (int j = 0; j < NJ; ++j) {
        const int t = t0 + wn * (TN / 2) + j * 16 + lt;
        f32x4 v = acc[i][j];
        if (isRes) {
          float* ptr = O0 + ((size_t)b * TP_ + t) * 128 + ml;
          float4 old = *(float4*)ptr;
          float nv[4] = {old.x + rsv * v[0] + cc[0], old.y + rsv * v[1] + cc[1],
                         old.z + rsv * v[2] + cc[2], old.w + rsv * v[3] + cc[3]};
          *(float4*)ptr = make_float4(nv[0], nv[1], nv[2], nv[3]);
          u16x4 pk;
#pragma unroll
          for (int r = 0; r < 4; ++r) pk[r] = f2bf(nv[r]);
          *(u16x4*)(Obf + ((size_t)b * TP_ + t) * 128 + ml) = pk;
          if constexpr (DUPF) {
            *(float4*)(p.dupO0 + ((size_t)b * TP_ + t) * 128 + ml) =
                make_float4(nv[0], nv[1], nv[2], nv[3]);
            *(u16x4*)(p.dupObf + ((size_t)b * TP_ + t) * 128 + ml) = pk;
          }
          if constexpr (WF) {
            if (t < T_) {
#pragma unroll
              for (int r = 0; r < 4; ++r)
                p.feat[((size_t)b * 128 + ml + r) * T_ + t] = nv[r];
            }
          }
        } else {
          float* ptr = O1 + ((size_t)b * TP_ + t) * 128 + ml;
          float nv[4];
          if constexpr (INITF) {
#pragma unroll
            for (int r = 0; r < 4; ++r) nv[r] = rsv * v[r] + cc[r];
          } else {
            float4 old = *(float4*)ptr;
            nv[0] = old.x + rsv * v[0] + cc[0];
            nv[1] = old.y + rsv * v[1] + cc[1];
            nv[2] = old.z + rsv * v[2] + cc[2];
            nv[3] = old.w + rsv * v[3] + cc[3];
          }
          *(float4*)ptr = make_float4(nv[0], nv[1], nv[2], nv[3]);
          if constexpr (DUPF) {
            *(float4*)(p.dupO1 + ((size_t)b * TP_ + t) * 128 + ml) =
                make_float4(nv[0], nv[1], nv[2], nv[3]);
          }
          if constexpr (SKBF) {
            const float aH = (br2 ? p.al1 : p.al0)[0];
            unsigned short* skb = br2 ? p.skb1 : p.skb0;
            u16x4 pk;
#pragma unroll
            for (int r = 0; r < 4; ++r) {
              float f = nv[r];
              f = f >= 0.f ? f : aH * f;
              pk[r] = f2bf(f);
            }
            *(u16x4*)(skb + ((size_t)b * TP_ + t) * 128 + ml) = pk;
          }
        }
      }
    }
  } else {  // EPI 3: heads scatter to [b][256][4000]
    float* O0 = br2 ? p.O0b : p.O0a;
    const float* bias = br2 ? p.bias1 : p.bias0;
#pragma unroll
    for (int i = 0; i < 4; ++i) {
      const int mg = m0 + wm * 64 + i * 16 + lg * 4;
#pragma unroll
      for (int j = 0; j < NJ; ++j) {
        const int t = t0 + wn * (TN / 2) + j * 16 + lt;
        if (t < T_) {
          f32x4 v = acc[i][j];
#pragma unroll
          for (int r = 0; r < 4; ++r)
            O0[((size_t)b * 256 + mg + r) * T_ + t] = v[r] + bias[mg + r];
        }
      }
    }
  }
}

// ---------------- depthwise dilated conv, [t][h], unconditional loads ------
__global__ __launch_bounds__(256) void dw3(
    const unsigned short* __restrict__ Y, unsigned short* __restrict__ U,
    const float* __restrict__ dww0, const float* __restrict__ dww1,
    const float* __restrict__ dwb0, const float* __restrict__ dwb1,
    const float* __restrict__ g10, const float* __restrict__ g11,
    const float* __restrict__ b10, const float* __restrict__ b11,
    const float* __restrict__ p20, const float* __restrict__ p21,
    const float* __restrict__ sIn0, const float* __restrict__ sIn1, float invN,
    float* __restrict__ sOut0, float* __restrict__ sOut1, int dil, int halfY) {
  const int q = blockIdx.y;
  const bool br2 = q >= halfY;
  const int b = br2 ? q - halfY : q;
  const float* dww = br2 ? dww1 : dww0;
  const float* dwb = br2 ? dwb1 : dwb0;
  const float* g1  = br2 ? g11 : g10;
  const float* b1  = br2 ? b11 : b10;
  const float* p2p = br2 ? p21 : p20;
  const float* sIn = br2 ? sIn1 : sIn0;
  float* sOut      = br2 ? sOut1 : sOut0;
  const int tid = threadIdx.x;
  const int hc = (tid & 63) * 8;
  const int tbase = blockIdx.x * 16 + (tid >> 6) * 4;

  float su, sq2;
  stats_sum(sIn, b, su, sq2);
  const float mean = su * invN;
  const float rs = rsqrtf(sq2 * invN - mean * mean + 1e-8f);
  float sA[8], oA[8], w0[8], w1[8], w2[8], bb[8];
#pragma unroll
  for (int j = 0; j < 8; ++j) {
    sA[j] = rs * g1[hc + j];
    oA[j] = b1[hc + j] - mean * sA[j];
    w0[j] = dww[(hc + j) * 3 + 0];
    w1[j] = dww[(hc + j) * 3 + 1];
    w2[j] = dww[(hc + j) * 3 + 2];
    bb[j] = dwb[hc + j];
  }
  const float alpha = p2p[0];
  const unsigned short* Yb = Y + (size_t)q * YSST;
  unsigned short* Ub = U + (size_t)q * USST;

  s8v xm[4], x0[4], xp[4];
#pragma unroll
  for (int i = 0; i < 4; ++i) {
    const int t = tbase + i;
    xm[i] = *(const s8v*)(Yb + (size_t)(t - dil) * YROW + hc);
    x0[i] = *(const s8v*)(Yb + (size_t)t * YROW + hc);
    xp[i] = *(const s8v*)(Yb + (size_t)(t + dil) * YROW + hc);
  }

  float s1 = 0.f, s2 = 0.f;
#pragma unroll
  for (int i = 0; i < 4; ++i) {
    const int t = tbase + i;
    const bool vm = (t - dil >= 0), vp = (t + dil < T_);
    s8v out;
#pragma unroll
    for (int j = 0; j < 8; ++j) {
      float fm = vm ? (bf2f((unsigned short)xm[i][j]) * sA[j] + oA[j]) : 0.f;
      float f0 = bf2f((unsigned short)x0[i][j]) * sA[j] + oA[j];
      float fp = vp ? (bf2f((unsigned short)xp[i][j]) * sA[j] + oA[j]) : 0.f;
      float v = fmaf(w0[j], fm, fmaf(w1[j], f0, fmaf(w2[j], fp, bb[j])));
      v = v >= 0.f ? v : alpha * v;
      unsigned short u = f2bf(v);
      out[j] = (short)u;
      float f = bf2f(u);
      s1 += f; s2 += f * f;
    }
    *(s8v*)(Ub + (size_t)t * YROW + hc) = out;
  }
#pragma unroll
  for (int off = 32; off > 0; off >>= 1) {
    s1 += __shfl_xor(s1, off);
    s2 += __shfl_xor(s2, off);
  }
  __shared__ float red[8];
  const int lane = tid & 63, wv = tid >> 6;
  if (lane == 0) { red[wv] = s1; red[4 + wv] = s2; }
  __syncthreads();
  if (tid == 0) {
    float* dst = sOut + (size_t)(blockIdx.x & (NSUB - 1)) * 8 + b * 2;
    atomicAdd(&dst[0], red[0] + red[1] + red[2] + red[3]);
    atomicAdd(&dst[1], red[4] + red[5] + red[6] + red[7]);
  }
}

// ---------------------------------------------------------------------------
extern "C" void kernel_launch(void* const* d_in, const int* in_sizes, int n_in,
                              void* d_out, int out_size, void* d_ws, size_t ws_size,
                              hipStream_t stream) {
  (void)in_sizes; (void)n_in; (void)out_size; (void)ws_size;
  const float* input = (const float*)d_in[0];
  const float* ln1_g = (const float*)d_in[1];
  const float* ln1_b = (const float*)d_in[2];
  const float* bn1_w = (const float*)d_in[3];
  const float* bn1_b = (const float*)d_in[4];
  const float* pw_w  = (const float*)d_in[5];
  const float* pw_b  = (const float*)d_in[6];
  const float* dw_w  = (const float*)d_in[7];
  const float* dw_b  = (const float*)d_in[8];
  const float* res_w = (const float*)d_in[9];
  const float* res_b = (const float*)d_in[10];
  const float* sk_w  = (const float*)d_in[11];
  const float* sk_b  = (const float*)d_in[12];
  const float* p1    = (const float*)d_in[13];
  const float* p2    = (const float*)d_in[14];
  const float* n1g   = (const float*)d_in[15];
  const float* n1b   = (const float*)d_in[16];
  const float* n2g   = (const float*)d_in[17];
  const float* n2b   = (const float*)d_in[18];
  const float* h1_p  = (const float*)d_in[19];
  const float* h1_w  = (const float*)d_in[20];
  const float* h1_b  = (const float*)d_in[21];
  const float* h2_p  = (const float*)d_in[22];
  const float* h2_w  = (const float*)d_in[23];
  const float* h2_b  = (const float*)d_in[24];

  float* out1 = (float*)d_out;
  float* out2 = out1 + 4096000;   // [4,256,4000]
  float* feat = out1 + 8192000;   // [4,128,4000]

  char* base = (char*)d_ws;
  float* OUTS  = (float*)base;                  base += (size_t)B_ * TP_ * 128 * 4;
  float* SKIP  = (float*)base;                  base += (size_t)B_ * TP_ * 128 * 4;
  float* OUT2  = (float*)base;                  base += (size_t)B_ * TP_ * 128 * 4;
  float* SKIP2 = (float*)base;                  base += (size_t)B_ * TP_ * 128 * 4;
  unsigned short* OUTbf  = (unsigned short*)base; base += (size_t)B_ * TP_ * 128 * 2;
  unsigned short* OUT2bf = (unsigned short*)base; base += (size_t)B_ * TP_ * 128 * 2;
  unsigned short* Ybuf = (unsigned short*)base; base += (size_t)8 * YSST * 2;  // 8 slots + halo
  unsigned short* Ubuf = (unsigned short*)base; base += (size_t)8 * USST * 2;  // 8 slots
  unsigned short* Xt   = (unsigned short*)base; base += (size_t)B_ * TP_ * 256 * 2;
  unsigned short* SKbf = (unsigned short*)base; base += (size_t)2 * B_ * TP_ * 128 * 2;
  unsigned short* Wpw  = (unsigned short*)base; base += (size_t)32 * 512 * 128 * 2;
  unsigned short* Wg   = (unsigned short*)base; base += (size_t)32 * 256 * 512 * 2;
  unsigned short* Wbn  = (unsigned short*)base; base += (size_t)128 * 256 * 2;
  unsigned short* Wh1  = (unsigned short*)base; base += (size_t)256 * 128 * 2;
  unsigned short* Wh2  = (unsigned short*)base; base += (size_t)256 * 128 * 2;
  float* UVu   = (float*)base;                  base += (size_t)32 * 256 * 4;
  float* UVv   = (float*)base;                  base += (size_t)32 * 256 * 4;
  float* STATS = (float*)base;

  unsigned short* YbufD = Ybuf + (size_t)YHAL * YROW;  // data base (halo before)
  const int npr = B_ * TP_ * 128;

  hipMemsetAsync(STATS, 0, (size_t)65 * SLOTW * sizeof(float), stream);

  const float invN_in = 1.0f / (256.0f * 4000.0f);
  const float invN_h  = 1.0f / (512.0f * 4000.0f);

  // weight prep (one merged cvt launch + fold)
  cvt4<<<2048, 256, 0, stream>>>(pw_w, Wpw, 32 * 512 * 128,
                                 bn1_w, Wbn, 128 * 256,
                                 h1_w, Wh1, 256 * 128,
                                 h2_w, Wh2, 256 * 128);
  fold_rs<<<32 * 256, 256, 0, stream>>>(res_w, sk_w, n2g, n2b, Wg, UVu, UVv);

  // input GN -> bf16 [t][256] -> bottleneck GEMM (K=256, BK=128, TN=64)
  gn_stats<<<dim3(64, B_), 256, 0, stream>>>(input, STATS, 256 * T_);
  tin<<<dim3(63, 4, B_), 256, 0, stream>>>(input, Xt, ln1_g, ln1_b, STATS, invN_in);
  {
    MMP q{}; q.A0 = Wbn; q.B0 = Xt; q.bias0 = bn1_b; q.O0a = OUTS; q.Obf0 = OUTbf;
    q.K = 256;
    mm6<0, 64, 0, 128><<<dim3(64, 1, B_), 256, 0, stream>>>(q);
  }

  // ---- serial blocks 0..15 (shared trunk)
  auto pw_one = [&](int i) {
    MMP q{}; q.A0 = Wpw + (size_t)i * 512 * 128; q.B0 = OUTbf;
    q.bias0 = pw_b + (size_t)i * 512; q.Obf0 = YbufD; q.al0 = p1 + i;
    q.so0 = STATS + (size_t)(1 + 2 * i) * SLOTW; q.K = 128;
    mm6<1, 128, 0, 64><<<dim3(32, 4, B_), 256, 0, stream>>>(q);
  };
  auto dw_one = [&](int i) {
    float* sA = STATS + (size_t)(1 + 2 * i) * SLOTW;
    float* sB = STATS + (size_t)(2 + 2 * i) * SLOTW;
    dw3<<<dim3(250, B_), 256, 0, stream>>>(
        YbufD, Ubuf, dw_w + (size_t)i * 512 * 3, nullptr,
        dw_b + (size_t)i * 512, nullptr, n1g + (size_t)i * 512, nullptr,
        n1b + (size_t)i * 512, nullptr, p2 + i, nullptr, sA, nullptr, invN_h,
        sB, nullptr, 1 << (i & 7), 99);
  };
  auto rs_one = [&](int i, int flg) {
    MMP q{}; q.A0 = Wg + (size_t)i * 256 * 512; q.B0 = Ubuf;
    q.O0a = OUTS; q.O1a = SKIP; q.Obf0 = OUTbf;
    q.si0 = STATS + (size_t)(2 + 2 * i) * SLOTW; q.invN = invN_h;
    q.Uc0 = UVu + (size_t)i * 256; q.Vc0 = UVv + (size_t)i * 256;
    q.rb0 = res_b + (size_t)i * 128; q.sb0 = sk_b + (size_t)i * 128;
    q.feat = feat; q.dupO0 = OUT2; q.dupObf = OUT2bf; q.dupO1 = SKIP2;
    q.K = 512;
    if (flg == 2)      mm6<2, 64, 2, 128><<<dim3(64, 2, B_), 256, 0, stream>>>(q);
    else if (flg == 4) mm6<2, 64, 4, 128><<<dim3(64, 2, B_), 256, 0, stream>>>(q);
    else if (flg == 8) mm6<2, 64, 8, 128><<<dim3(64, 2, B_), 256, 0, stream>>>(q);
    else               mm6<2, 64, 0, 128><<<dim3(64, 2, B_), 256, 0, stream>>>(q);
  };

  for (int i = 0; i < 16; ++i) {
    pw_one(i);
    dw_one(i);
    rs_one(i, (i == 0) ? 8 : (i == 7) ? 2 : (i == 15) ? 4 : 0);
  }

  // ---- paired blocks: branch1 = 16+j, branch2 = 24+j
  for (int j = 0; j < 8; ++j) {
    const int i1 = 16 + j, i2 = 24 + j;
    float* sA1 = STATS + (size_t)(1 + 2 * i1) * SLOTW;
    float* sB1 = STATS + (size_t)(2 + 2 * i1) * SLOTW;
    float* sA2 = STATS + (size_t)(1 + 2 * i2) * SLOTW;
    float* sB2 = STATS + (size_t)(2 + 2 * i2) * SLOTW;
    {
      MMP q{};
      q.A0 = Wpw + (size_t)i1 * 512 * 128; q.A1 = Wpw + (size_t)i2 * 512 * 128;
      q.B0 = OUTbf; q.B1 = OUT2bf;
      q.bias0 = pw_b + (size_t)i1 * 512; q.bias1 = pw_b + (size_t)i2 * 512;
      q.Obf0 = YbufD; q.Obf1 = YbufD + 4 * YSST;
      q.al0 = p1 + i1; q.al1 = p1 + i2;
      q.so0 = sA1; q.so1 = sA2; q.K = 128;
      mm6<1, 128, 1, 64><<<dim3(32, 4, 2 * B_), 256, 0, stream>>>(q);
    }
    dw3<<<dim3(250, 2 * B_), 256, 0, stream>>>(
        YbufD, Ubuf,
        dw_w + (size_t)i1 * 512 * 3, dw_w + (size_t)i2 * 512 * 3,
        dw_b + (size_t)i1 * 512, dw_b + (size_t)i2 * 512,
        n1g + (size_t)i1 * 512, n1g + (size_t)i2 * 512,
        n1b + (size_t)i1 * 512, n1b + (size_t)i2 * 512,
        p2 + i1, p2 + i2, sA1, sA2, invN_h, sB1, sB2, 1 << (j & 7), B_);
    {
      MMP q{};
      q.A0 = Wg + (size_t)i1 * 256 * 512; q.A1 = Wg + (size_t)i2 * 256 * 512;
      q.B0 = Ubuf; q.B1 = Ubuf + 4 * USST;
      q.O0a = OUTS; q.O0b = OUT2; q.O1a = SKIP; q.O1b = SKIP2;
      q.Obf0 = OUTbf; q.Obf1 = OUT2bf;
      q.si0 = sB1; q.si1 = sB2; q.invN = invN_h;
      q.Uc0 = UVu + (size_t)i1 * 256; q.Uc1 = UVu + (size_t)i2 * 256;
      q.Vc0 = UVv + (size_t)i1 * 256; q.Vc1 = UVv + (size_t)i2 * 256;
      q.rb0 = res_b + (size_t)i1 * 128; q.rb1 = res_b + (size_t)i2 * 128;
      q.sb0 = sk_b + (size_t)i1 * 128; q.sb1 = sk_b + (size_t)i2 * 128;
      q.K = 512;
      if (j == 7) {
        // final skip update: also emit heads input SKbf = f2bf(prelu(nv))
        q.al0 = h1_p; q.al1 = h2_p;
        q.skb0 = SKbf; q.skb1 = SKbf + npr;
        mm6<2, 128, 17, 128><<<dim3(32, 2, 2 * B_), 256, 0, stream>>>(q);
      } else {
        mm6<2, 128, 1, 128><<<dim3(32, 2, 2 * B_), 256, 0, stream>>>(q);
      }
    }
  }

  // ---- heads (both in one pass; SKbf written by j=7 rs epilogue)
  {
    MMP q{};
    q.A0 = Wh1; q.A1 = Wh2;
    q.B0 = SKbf; q.B1 = SKbf + npr;
    q.bias0 = h1_b; q.bias1 = h2_b;
    q.O0a = out1; q.O0b = out2; q.K = 128;
    mm6<3, 128, 1, 64><<<dim3(32, 2, 2 * B_), 256, 0, stream>>>(q);
  }
}

// Round 15
// 1225.867 us; speedup vs baseline: 1.0689x; 1.0001x over previous
//
#include <hip/hip_runtime.h>
#include <hip/hip_bf16.h>

// ---------------------------------------------------------------------------
// Conv-TasNet TCN, bf16-MFMA v14 = r14 (1226us verified) + BK=128 on ALL
// K=128 GEMMs (serial pw, paired pw, heads): single K-step, one barrier pair.
// LDS 64KB = 2 blocks/CU = exact grid residency (512 blocks). Same mm6 core,
// same sync structure, same math.
// ---------------------------------------------------------------------------

#define T_  4000
#define TP_ 4096
#define B_  4
#define YHAL 128
#define YROW 512
#define YSST ((size_t)(TP_ + 2 * YHAL) * YROW)
#define USST ((size_t)TP_ * YROW)
#define NSUB 64
#define SLOTW (NSUB * 8)

typedef __attribute__((ext_vector_type(8))) short  s8v;
typedef __attribute__((ext_vector_type(4))) float  f32x4;
typedef __attribute__((ext_vector_type(4))) unsigned short u16x4;

__device__ __forceinline__ float bf2f(unsigned short u) {
  unsigned int i = ((unsigned int)u) << 16;
  float f; __builtin_memcpy(&f, &i, 4); return f;
}
__device__ __forceinline__ unsigned short f2bf(float f) {
  unsigned int i; __builtin_memcpy(&i, &f, 4);
  unsigned int r = i + 0x7fffu + ((i >> 16) & 1u);
  return (unsigned short)(r >> 16);
}

__device__ __forceinline__ void g2lds16(const void* g, void* l) {
  __builtin_amdgcn_global_load_lds(
      (const __attribute__((address_space(1))) unsigned int*)g,
      (__attribute__((address_space(3))) unsigned int*)l, 16, 0, 0);
}

// consumer-side: sum the 64 sub-slot partials of one stats slot (per-wave).
__device__ __forceinline__ void stats_sum(const float* __restrict__ si, int b,
                                          float& u, float& q) {
  const int lane = threadIdx.x & 63;
  u = si[lane * 8 + b * 2 + 0];
  q = si[lane * 8 + b * 2 + 1];
#pragma unroll
  for (int off = 32; off > 0; off >>= 1) {
    u += __shfl_xor(u, off);
    q += __shfl_xor(q, off);
  }
}

// ---------------- per-sample sum/sumsq over contiguous [C*T] ---------------
__global__ __launch_bounds__(256) void gn_stats(const float* __restrict__ X,
                                                float* __restrict__ statsOut, int n) {
  const int b = blockIdx.y;
  const float4* xp = (const float4*)(X + (size_t)b * n);
  const int n4 = n >> 2;
  float s1 = 0.f, s2 = 0.f;
  for (int idx = blockIdx.x * 256 + threadIdx.x; idx < n4; idx += gridDim.x * 256) {
    float4 v = xp[idx];
    s1 += v.x + v.y + v.z + v.w;
    s2 += v.x * v.x + v.y * v.y + v.z * v.z + v.w * v.w;
  }
#pragma unroll
  for (int off = 32; off > 0; off >>= 1) {
    s1 += __shfl_xor(s1, off);
    s2 += __shfl_xor(s2, off);
  }
  __shared__ float red[8];
  const int lane = threadIdx.x & 63, wv = threadIdx.x >> 6;
  if (lane == 0) { red[wv] = s1; red[4 + wv] = s2; }
  __syncthreads();
  if (threadIdx.x == 0) {
    float* dst = statsOut + (size_t)(blockIdx.x & (NSUB - 1)) * 8 + b * 2;
    atomicAdd(&dst[0], red[0] + red[1] + red[2] + red[3]);
    atomicAdd(&dst[1], red[4] + red[5] + red[6] + red[7]);
  }
}

// ---------------- weight prep: 4 fp32->bf16 conversions in one launch ------
__global__ __launch_bounds__(256) void cvt4(
    const float* __restrict__ s0, unsigned short* __restrict__ d0, int n0,
    const float* __restrict__ s1, unsigned short* __restrict__ d1, int n1,
    const float* __restrict__ s2, unsigned short* __restrict__ d2, int n2,
    const float* __restrict__ s3, unsigned short* __restrict__ d3, int n3) {
  const int total = n0 + n1 + n2 + n3;
  for (int i = blockIdx.x * 256 + threadIdx.x; i < total; i += gridDim.x * 256) {
    int j = i;
    if (j < n0) { d0[j] = f2bf(s0[j]); continue; }
    j -= n0;
    if (j < n1) { d1[j] = f2bf(s1[j]); continue; }
    j -= n1;
    if (j < n2) { d2[j] = f2bf(s2[j]); continue; }
    j -= n2;
    d3[j] = f2bf(s3[j]);
  }
}

__global__ __launch_bounds__(256) void fold_rs(
    const float* __restrict__ rw, const float* __restrict__ sw,
    const float* __restrict__ g2a, const float* __restrict__ b2a,
    unsigned short* __restrict__ Wg, float* __restrict__ Ucb,
    float* __restrict__ Vcb) {
  const int row = blockIdx.x;                 // i*256 + m
  const int i = row >> 8, m = row & 255;
  const float* src = (m < 128) ? rw + ((size_t)i * 128 + m) * 512
                               : sw + ((size_t)i * 128 + (m - 128)) * 512;
  const float* g = g2a + (size_t)i * 512;
  const float* bb = b2a + (size_t)i * 512;
  unsigned short* dst = Wg + (size_t)row * 512;
  float u = 0.f, v = 0.f;
  for (int h = threadIdx.x; h < 512; h += 256) {
    float wgt = src[h] * g[h];
    dst[h] = f2bf(wgt);
    u += wgt; v += src[h] * bb[h];
  }
#pragma unroll
  for (int off = 32; off > 0; off >>= 1) {
    u += __shfl_xor(u, off);
    v += __shfl_xor(v, off);
  }
  __shared__ float red[8];
  const int lane = threadIdx.x & 63, wv = threadIdx.x >> 6;
  if (lane == 0) { red[wv] = u; red[4 + wv] = v; }
  __syncthreads();
  if (threadIdx.x == 0) {
    Ucb[row] = red[0] + red[1] + red[2] + red[3];
    Vcb[row] = red[4] + red[5] + red[6] + red[7];
  }
}

// ---------------- input transpose + GN affine + bf16 -----------------------
__global__ __launch_bounds__(256) void tin(const float* __restrict__ X,
                                           unsigned short* __restrict__ Xt,
                                           const float* __restrict__ g,
                                           const float* __restrict__ bt,
                                           const float* __restrict__ sIn, float invN) {
  const int b = blockIdx.z, c0 = blockIdx.y * 64, t0 = blockIdx.x * 64;
  __shared__ float tile[64][65];
  const int tid = threadIdx.x;
  float su, sq;
  stats_sum(sIn, b, su, sq);
  const float mean = su * invN;
  const float rs = rsqrtf(sq * invN - mean * mean + 1e-8f);
  {
    const int cl = tid >> 2, tq = (tid & 3) * 16;
    const float* Xr = X + ((size_t)b * 256 + c0 + cl) * T_;
#pragma unroll
    for (int j = 0; j < 4; ++j) {
      int tt = t0 + tq + j * 4;
      float4 v;
      if (tt + 3 < T_) v = *(const float4*)(Xr + tt);
      else {
        v.x = (tt + 0 < T_) ? Xr[tt + 0] : 0.f;
        v.y = (tt + 1 < T_) ? Xr[tt + 1] : 0.f;
        v.z = (tt + 2 < T_) ? Xr[tt + 2] : 0.f;
        v.w = (tt + 3 < T_) ? Xr[tt + 3] : 0.f;
      }
      tile[cl][tq + j * 4 + 0] = v.x; tile[cl][tq + j * 4 + 1] = v.y;
      tile[cl][tq + j * 4 + 2] = v.z; tile[cl][tq + j * 4 + 3] = v.w;
    }
  }
  __syncthreads();
  {
    const int tl = tid >> 2, cq = (tid & 3) * 16;
    const int t = t0 + tl;
    if (t < T_) {
      unsigned short* dst = Xt + ((size_t)b * TP_ + t) * 256 + c0 + cq;
      s8v u0, u1;
#pragma unroll
      for (int j = 0; j < 16; ++j) {
        int c = c0 + cq + j;
        float sc = rs * g[c];
        float oc = bt[c] - mean * sc;
        unsigned short uu = f2bf(tile[cq + j][tl] * sc + oc);
        if (j < 8) u0[j] = (short)uu; else u1[j - 8] = (short)uu;
      }
      *(s8v*)dst = u0;
      *(s8v*)(dst + 8) = u1;
    }
  }
}

// ---------------- mm6 params ------------------------------------------------
struct MMP {
  const unsigned short *A0, *A1, *B0, *B1;
  const float *bias0, *bias1;
  float *O0a, *O0b, *O1a, *O1b;
  unsigned short *Obf0, *Obf1;
  const float *al0, *al1;
  float *so0, *so1;
  const float *si0, *si1;
  const float *Uc0, *Uc1, *Vc0, *Vc1, *rb0, *rb1, *sb0, *sb1;
  float* feat;
  float* dupO0; unsigned short* dupObf; float* dupO1;
  unsigned short *skb0, *skb1;
  int K; float invN;
};

// ---------------- clean bf16 MFMA GEMM, 128m x TNt x BKk, single-buffer ----
// EPI 0: O0 fp32 [t][128] = v+bias, Obf shadow                (bn1)
// EPI 1: prelu -> Obf bf16 Y-slot (halo stride YSST) + GN stats (pw)
// EPI 2: GN2-folded; y==0: res RMW O0 + shadow; y==1: skip RMW O1
//        WF: also feat; DUP: fork copies; INIT: skip WRITE (no RMW);
//        SKB: skip also emits f2bf(prelu(nv)) to skb (heads input)
// EPI 3: masked fp32 scatter O0[b][256][4000] = v+bias         (heads)
// FLG bits: 1=PAIR 2=WF 4=DUP 8=INIT 16=SKB
template <int EPI, int TN, int FLG, int BK>
__global__ __launch_bounds__(256) void mm6(MMP p) {
  constexpr bool PAIR  = (FLG & 1) != 0;
  constexpr bool WF    = (FLG & 2) != 0;
  constexpr bool DUPF  = (FLG & 4) != 0;
  constexpr bool INITF = (FLG & 8) != 0;
  constexpr bool SKBF  = (FLG & 16) != 0;
  constexpr int NJ = TN / 32;
  constexpr int KH = BK / 64;
  __shared__ unsigned short As[KH * 128 * 64];
  __shared__ unsigned short Bs[KH * TN * 64];
  __shared__ float redw[8];
  int b = blockIdx.z; bool br2 = false;
  if constexpr (PAIR) {
    const int h = gridDim.z >> 1;
    if (b >= h) { br2 = true; b -= h; }
  }
  const int K = p.K;
  const unsigned short* A  = br2 ? p.A1 : p.A0;
  const unsigned short* Bm = br2 ? p.B1 : p.B0;
  const int m0 = blockIdx.y * 128;
  const int t0 = blockIdx.x * TN;
  const int tid = threadIdx.x;
  const int lane = tid & 63;
  const int w = tid >> 6;
  const int wm = w >> 1, wn = w & 1;
  const int lt = lane & 15, lg = lane >> 4;
  const unsigned short* Ab = A + (size_t)m0 * K;
  const unsigned short* Bb = Bm + ((size_t)b * TP_ + t0) * K;
  const int srow8 = lane >> 3;
  const int skc   = ((lane & 7) ^ (lane >> 3)) * 8;

  f32x4 acc[4][NJ];
#pragma unroll
  for (int i = 0; i < 4; ++i)
#pragma unroll
    for (int j = 0; j < NJ; ++j) acc[i][j] = (f32x4){0.f, 0.f, 0.f, 0.f};

  for (int k0 = 0; k0 < K; k0 += BK) {
#pragma unroll
    for (int kh = 0; kh < KH; ++kh) {
#pragma unroll
      for (int c = 0; c < 4; ++c) {
        const int ch = w * 4 + c;
        g2lds16(Ab + (size_t)(ch * 8 + srow8) * K + k0 + kh * 64 + skc,
                &As[kh * 8192 + ch * 512]);
      }
#pragma unroll
      for (int c = 0; c < NJ; ++c) {
        const int ch = w * NJ + c;
        g2lds16(Bb + (size_t)(ch * 8 + srow8) * K + k0 + kh * 64 + skc,
                &Bs[kh * TN * 64 + ch * 512]);
      }
    }
    __syncthreads();
#pragma unroll
    for (int kss = 0; kss < 2 * KH; ++kss) {
      const int kh = kss >> 1, ks = kss & 1;
      s8v bfr[NJ];
#pragma unroll
      for (int j = 0; j < NJ; ++j) {
        const int R = wn * (TN / 2) + j * 16 + lt;
        bfr[j] = *(const s8v*)&Bs[kh * TN * 64 + R * 64 + (((ks * 4 + lg) ^ (R & 7)) * 8)];
      }
#pragma unroll
      for (int i = 0; i < 4; ++i) {
        const int R = wm * 64 + i * 16 + lt;
        s8v af = *(const s8v*)&As[kh * 8192 + R * 64 + (((ks * 4 + lg) ^ (R & 7)) * 8)];
#pragma unroll
        for (int j = 0; j < NJ; ++j)
          acc[i][j] = __builtin_amdgcn_mfma_f32_16x16x32_bf16(af, bfr[j], acc[i][j], 0, 0, 0);
      }
    }
    __syncthreads();
  }

  if constexpr (EPI == 0) {
    const float* bias = p.bias0;
#pragma unroll
    for (int i = 0; i < 4; ++i) {
      const int mg = m0 + wm * 64 + i * 16 + lg * 4;
      float4 bi = *(const float4*)(bias + mg);
#pragma unroll
      for (int j = 0; j < NJ; ++j) {
        const int t = t0 + wn * (TN / 2) + j * 16 + lt;
        f32x4 v = acc[i][j];
        float nv[4] = {v[0] + bi.x, v[1] + bi.y, v[2] + bi.z, v[3] + bi.w};
        *(float4*)(p.O0a + ((size_t)b * TP_ + t) * 128 + mg) =
            make_float4(nv[0], nv[1], nv[2], nv[3]);
        u16x4 pk;
#pragma unroll
        for (int r = 0; r < 4; ++r) pk[r] = f2bf(nv[r]);
        *(u16x4*)(p.Obf0 + ((size_t)b * TP_ + t) * 128 + mg) = pk;
      }
    }
  } else if constexpr (EPI == 1) {
    const float* bias = br2 ? p.bias1 : p.bias0;
    unsigned short* Obf = (br2 ? p.Obf1 : p.Obf0) + (size_t)b * YSST;
    const float aO = (br2 ? p.al1 : p.al0)[0];
    float* so = br2 ? p.so1 : p.so0;
    float s1 = 0.f, s2 = 0.f;
#pragma unroll
    for (int i = 0; i < 4; ++i) {
      const int mg = m0 + wm * 64 + i * 16 + lg * 4;
      float4 bi = *(const float4*)(bias + mg);
      float bv[4] = {bi.x, bi.y, bi.z, bi.w};
#pragma unroll
      for (int j = 0; j < NJ; ++j) {
        const int t = t0 + wn * (TN / 2) + j * 16 + lt;
        f32x4 v = acc[i][j];
        u16x4 pk;
#pragma unroll
        for (int r = 0; r < 4; ++r) {
          float f = v[r] + bv[r];
          f = f >= 0.f ? f : aO * f;
          pk[r] = f2bf(f);
        }
        *(u16x4*)(Obf + (size_t)t * YROW + mg) = pk;
        if (t < T_) {
#pragma unroll
          for (int r = 0; r < 4; ++r) { float f = bf2f(pk[r]); s1 += f; s2 += f * f; }
        }
      }
    }
#pragma unroll
    for (int off = 32; off > 0; off >>= 1) {
      s1 += __shfl_xor(s1, off);
      s2 += __shfl_xor(s2, off);
    }
    if (lane == 0) { redw[w] = s1; redw[4 + w] = s2; }
    __syncthreads();
    if (tid == 0) {
      float* dst = so + (size_t)(blockIdx.x & (NSUB - 1)) * 8 + b * 2;
      atomicAdd(&dst[0], redw[0] + redw[1] + redw[2] + redw[3]);
      atomicAdd(&dst[1], redw[4] + redw[5] + redw[6] + redw[7]);
    }
  } else if constexpr (EPI == 2) {
    float* O0 = br2 ? p.O0b : p.O0a;
    float* O1 = br2 ? p.O1b : p.O1a;
    unsigned short* Obf = br2 ? p.Obf1 : p.Obf0;
    const float* si = br2 ? p.si1 : p.si0;
    const float* Uc = br2 ? p.Uc1 : p.Uc0;
    const float* Vc = br2 ? p.Vc1 : p.Vc0;
    const float* rb = br2 ? p.rb1 : p.rb0;
    const float* sb = br2 ? p.sb1 : p.sb0;
    float su, sq;
    stats_sum(si, b, su, sq);
    const float mean = su * p.invN;
    const float rsv = rsqrtf(sq * p.invN - mean * mean + 1e-8f);
    const bool isRes = (m0 == 0);
#pragma unroll
    for (int i = 0; i < 4; ++i) {
      const int ml = wm * 64 + i * 16 + lg * 4;   // 0..127 local
      float cc[4];
#pragma unroll
      for (int r = 0; r < 4; ++r) {
        const int mgG = m0 + ml + r;
        cc[r] = Vc[mgG] - mean * rsv * Uc[mgG] + (isRes ? rb[ml + r] : sb[ml + r]);
      }
#pragma unroll
      for (int j = 0; j < NJ; ++j) {
        const int t = t0 + wn * (TN / 2) + j * 16 + lt;
        f32x4 v = acc[i][j];
        if (isRes) {
          float* ptr = O0 + ((size_t)b * TP_ + t) * 128 + ml;
          float4 old = *(float4*)ptr;
          float nv[4] = {old.x + rsv * v[0] + cc[0], old.y + rsv * v[1] + cc[1],
                         old.z + rsv * v[2] + cc[2], old.w + rsv * v[3] + cc[3]};
          *(float4*)ptr = make_float4(nv[0], nv[1], nv[2], nv[3]);
          u16x4 pk;
#pragma unroll
          for (int r = 0; r < 4; ++r) pk[r] = f2bf(nv[r]);
          *(u16x4*)(Obf + ((size_t)b * TP_ + t) * 128 + ml) = pk;
          if constexpr (DUPF) {
            *(float4*)(p.dupO0 + ((size_t)b * TP_ + t) * 128 + ml) =
                make_float4(nv[0], nv[1], nv[2], nv[3]);
            *(u16x4*)(p.dupObf + ((size_t)b * TP_ + t) * 128 + ml) = pk;
          }
          if constexpr (WF) {
            if (t < T_) {
#pragma unroll
              for (int r = 0; r < 4; ++r)
                p.feat[((size_t)b * 128 + ml + r) * T_ + t] = nv[r];
            }
          }
        } else {
          float* ptr = O1 + ((size_t)b * TP_ + t) * 128 + ml;
          float nv[4];
          if constexpr (INITF) {
#pragma unroll
            for (int r = 0; r < 4; ++r) nv[r] = rsv * v[r] + cc[r];
          } else {
            float4 old = *(float4*)ptr;
            nv[0] = old.x + rsv * v[0] + cc[0];
            nv[1] = old.y + rsv * v[1] + cc[1];
            nv[2] = old.z + rsv * v[2] + cc[2];
            nv[3] = old.w + rsv * v[3] + cc[3];
          }
          *(float4*)ptr = make_float4(nv[0], nv[1], nv[2], nv[3]);
          if constexpr (DUPF) {
            *(float4*)(p.dupO1 + ((size_t)b * TP_ + t) * 128 + ml) =
                make_float4(nv[0], nv[1], nv[2], nv[3]);
          }
          if constexpr (SKBF) {
            const float aH = (br2 ? p.al1 : p.al0)[0];
            unsigned short* skb = br2 ? p.skb1 : p.skb0;
            u16x4 pk;
#pragma unroll
            for (int r = 0; r < 4; ++r) {
              float f = nv[r];
              f = f >= 0.f ? f : aH * f;
              pk[r] = f2bf(f);
            }
            *(u16x4*)(skb + ((size_t)b * TP_ + t) * 128 + ml) = pk;
          }
        }
      }
    }
  } else {  // EPI 3: heads scatter to [b][256][4000]
    float* O0 = br2 ? p.O0b : p.O0a;
    const float* bias = br2 ? p.bias1 : p.bias0;
#pragma unroll
    for (int i = 0; i < 4; ++i) {
      const int mg = m0 + wm * 64 + i * 16 + lg * 4;
#pragma unroll
      for (int j = 0; j < NJ; ++j) {
        const int t = t0 + wn * (TN / 2) + j * 16 + lt;
        if (t < T_) {
          f32x4 v = acc[i][j];
#pragma unroll
          for (int r = 0; r < 4; ++r)
            O0[((size_t)b * 256 + mg + r) * T_ + t] = v[r] + bias[mg + r];
        }
      }
    }
  }
}

// ---------------- depthwise dilated conv, [t][h], unconditional loads ------
__global__ __launch_bounds__(256) void dw3(
    const unsigned short* __restrict__ Y, unsigned short* __restrict__ U,
    const float* __restrict__ dww0, const float* __restrict__ dww1,
    const float* __restrict__ dwb0, const float* __restrict__ dwb1,
    const float* __restrict__ g10, const float* __restrict__ g11,
    const float* __restrict__ b10, const float* __restrict__ b11,
    const float* __restrict__ p20, const float* __restrict__ p21,
    const float* __restrict__ sIn0, const float* __restrict__ sIn1, float invN,
    float* __restrict__ sOut0, float* __restrict__ sOut1, int dil, int halfY) {
  const int q = blockIdx.y;
  const bool br2 = q >= halfY;
  const int b = br2 ? q - halfY : q;
  const float* dww = br2 ? dww1 : dww0;
  const float* dwb = br2 ? dwb1 : dwb0;
  const float* g1  = br2 ? g11 : g10;
  const float* b1  = br2 ? b11 : b10;
  const float* p2p = br2 ? p21 : p20;
  const float* sIn = br2 ? sIn1 : sIn0;
  float* sOut      = br2 ? sOut1 : sOut0;
  const int tid = threadIdx.x;
  const int hc = (tid & 63) * 8;
  const int tbase = blockIdx.x * 16 + (tid >> 6) * 4;

  float su, sq2;
  stats_sum(sIn, b, su, sq2);
  const float mean = su * invN;
  const float rs = rsqrtf(sq2 * invN - mean * mean + 1e-8f);
  float sA[8], oA[8], w0[8], w1[8], w2[8], bb[8];
#pragma unroll
  for (int j = 0; j < 8; ++j) {
    sA[j] = rs * g1[hc + j];
    oA[j] = b1[hc + j] - mean * sA[j];
    w0[j] = dww[(hc + j) * 3 + 0];
    w1[j] = dww[(hc + j) * 3 + 1];
    w2[j] = dww[(hc + j) * 3 + 2];
    bb[j] = dwb[hc + j];
  }
  const float alpha = p2p[0];
  const unsigned short* Yb = Y + (size_t)q * YSST;
  unsigned short* Ub = U + (size_t)q * USST;

  s8v xm[4], x0[4], xp[4];
#pragma unroll
  for (int i = 0; i < 4; ++i) {
    const int t = tbase + i;
    xm[i] = *(const s8v*)(Yb + (size_t)(t - dil) * YROW + hc);
    x0[i] = *(const s8v*)(Yb + (size_t)t * YROW + hc);
    xp[i] = *(const s8v*)(Yb + (size_t)(t + dil) * YROW + hc);
  }

  float s1 = 0.f, s2 = 0.f;
#pragma unroll
  for (int i = 0; i < 4; ++i) {
    const int t = tbase + i;
    const bool vm = (t - dil >= 0), vp = (t + dil < T_);
    s8v out;
#pragma unroll
    for (int j = 0; j < 8; ++j) {
      float fm = vm ? (bf2f((unsigned short)xm[i][j]) * sA[j] + oA[j]) : 0.f;
      float f0 = bf2f((unsigned short)x0[i][j]) * sA[j] + oA[j];
      float fp = vp ? (bf2f((unsigned short)xp[i][j]) * sA[j] + oA[j]) : 0.f;
      float v = fmaf(w0[j], fm, fmaf(w1[j], f0, fmaf(w2[j], fp, bb[j])));
      v = v >= 0.f ? v : alpha * v;
      unsigned short u = f2bf(v);
      out[j] = (short)u;
      float f = bf2f(u);
      s1 += f; s2 += f * f;
    }
    *(s8v*)(Ub + (size_t)t * YROW + hc) = out;
  }
#pragma unroll
  for (int off = 32; off > 0; off >>= 1) {
    s1 += __shfl_xor(s1, off);
    s2 += __shfl_xor(s2, off);
  }
  __shared__ float red[8];
  const int lane = tid & 63, wv = tid >> 6;
  if (lane == 0) { red[wv] = s1; red[4 + wv] = s2; }
  __syncthreads();
  if (tid == 0) {
    float* dst = sOut + (size_t)(blockIdx.x & (NSUB - 1)) * 8 + b * 2;
    atomicAdd(&dst[0], red[0] + red[1] + red[2] + red[3]);
    atomicAdd(&dst[1], red[4] + red[5] + red[6] + red[7]);
  }
}

// ---------------------------------------------------------------------------
extern "C" void kernel_launch(void* const* d_in, const int* in_sizes, int n_in,
                              void* d_out, int out_size, void* d_ws, size_t ws_size,
                              hipStream_t stream) {
  (void)in_sizes; (void)n_in; (void)out_size; (void)ws_size;
  const float* input = (const float*)d_in[0];
  const float* ln1_g = (const float*)d_in[1];
  const float* ln1_b = (const float*)d_in[2];
  const float* bn1_w = (const float*)d_in[3];
  const float* bn1_b = (const float*)d_in[4];
  const float* pw_w  = (const float*)d_in[5];
  const float* pw_b  = (const float*)d_in[6];
  const float* dw_w  = (const float*)d_in[7];
  const float* dw_b  = (const float*)d_in[8];
  const float* res_w = (const float*)d_in[9];
  const float* res_b = (const float*)d_in[10];
  const float* sk_w  = (const float*)d_in[11];
  const float* sk_b  = (const float*)d_in[12];
  const float* p1    = (const float*)d_in[13];
  const float* p2    = (const float*)d_in[14];
  const float* n1g   = (const float*)d_in[15];
  const float* n1b   = (const float*)d_in[16];
  const float* n2g   = (const float*)d_in[17];
  const float* n2b   = (const float*)d_in[18];
  const float* h1_p  = (const float*)d_in[19];
  const float* h1_w  = (const float*)d_in[20];
  const float* h1_b  = (const float*)d_in[21];
  const float* h2_p  = (const float*)d_in[22];
  const float* h2_w  = (const float*)d_in[23];
  const float* h2_b  = (const float*)d_in[24];

  float* out1 = (float*)d_out;
  float* out2 = out1 + 4096000;   // [4,256,4000]
  float* feat = out1 + 8192000;   // [4,128,4000]

  char* base = (char*)d_ws;
  float* OUTS  = (float*)base;                  base += (size_t)B_ * TP_ * 128 * 4;
  float* SKIP  = (float*)base;                  base += (size_t)B_ * TP_ * 128 * 4;
  float* OUT2  = (float*)base;                  base += (size_t)B_ * TP_ * 128 * 4;
  float* SKIP2 = (float*)base;                  base += (size_t)B_ * TP_ * 128 * 4;
  unsigned short* OUTbf  = (unsigned short*)base; base += (size_t)B_ * TP_ * 128 * 2;
  unsigned short* OUT2bf = (unsigned short*)base; base += (size_t)B_ * TP_ * 128 * 2;
  unsigned short* Ybuf = (unsigned short*)base; base += (size_t)8 * YSST * 2;  // 8 slots + halo
  unsigned short* Ubuf = (unsigned short*)base; base += (size_t)8 * USST * 2;  // 8 slots
  unsigned short* Xt   = (unsigned short*)base; base += (size_t)B_ * TP_ * 256 * 2;
  unsigned short* SKbf = (unsigned short*)base; base += (size_t)2 * B_ * TP_ * 128 * 2;
  unsigned short* Wpw  = (unsigned short*)base; base += (size_t)32 * 512 * 128 * 2;
  unsigned short* Wg   = (unsigned short*)base; base += (size_t)32 * 256 * 512 * 2;
  unsigned short* Wbn  = (unsigned short*)base; base += (size_t)128 * 256 * 2;
  unsigned short* Wh1  = (unsigned short*)base; base += (size_t)256 * 128 * 2;
  unsigned short* Wh2  = (unsigned short*)base; base += (size_t)256 * 128 * 2;
  float* UVu   = (float*)base;                  base += (size_t)32 * 256 * 4;
  float* UVv   = (float*)base;                  base += (size_t)32 * 256 * 4;
  float* STATS = (float*)base;

  unsigned short* YbufD = Ybuf + (size_t)YHAL * YROW;  // data base (halo before)
  const int npr = B_ * TP_ * 128;

  hipMemsetAsync(STATS, 0, (size_t)65 * SLOTW * sizeof(float), stream);

  const float invN_in = 1.0f / (256.0f * 4000.0f);
  const float invN_h  = 1.0f / (512.0f * 4000.0f);

  // weight prep (one merged cvt launch + fold)
  cvt4<<<2048, 256, 0, stream>>>(pw_w, Wpw, 32 * 512 * 128,
                                 bn1_w, Wbn, 128 * 256,
                                 h1_w, Wh1, 256 * 128,
                                 h2_w, Wh2, 256 * 128);
  fold_rs<<<32 * 256, 256, 0, stream>>>(res_w, sk_w, n2g, n2b, Wg, UVu, UVv);

  // input GN -> bf16 [t][256] -> bottleneck GEMM (K=256, BK=128, TN=64)
  gn_stats<<<dim3(64, B_), 256, 0, stream>>>(input, STATS, 256 * T_);
  tin<<<dim3(63, 4, B_), 256, 0, stream>>>(input, Xt, ln1_g, ln1_b, STATS, invN_in);
  {
    MMP q{}; q.A0 = Wbn; q.B0 = Xt; q.bias0 = bn1_b; q.O0a = OUTS; q.Obf0 = OUTbf;
    q.K = 256;
    mm6<0, 64, 0, 128><<<dim3(64, 1, B_), 256, 0, stream>>>(q);
  }

  // ---- serial blocks 0..15 (shared trunk)
  auto pw_one = [&](int i) {
    MMP q{}; q.A0 = Wpw + (size_t)i * 512 * 128; q.B0 = OUTbf;
    q.bias0 = pw_b + (size_t)i * 512; q.Obf0 = YbufD; q.al0 = p1 + i;
    q.so0 = STATS + (size_t)(1 + 2 * i) * SLOTW; q.K = 128;
    mm6<1, 128, 0, 128><<<dim3(32, 4, B_), 256, 0, stream>>>(q);
  };
  auto dw_one = [&](int i) {
    float* sA = STATS + (size_t)(1 + 2 * i) * SLOTW;
    float* sB = STATS + (size_t)(2 + 2 * i) * SLOTW;
    dw3<<<dim3(250, B_), 256, 0, stream>>>(
        YbufD, Ubuf, dw_w + (size_t)i * 512 * 3, nullptr,
        dw_b + (size_t)i * 512, nullptr, n1g + (size_t)i * 512, nullptr,
        n1b + (size_t)i * 512, nullptr, p2 + i, nullptr, sA, nullptr, invN_h,
        sB, nullptr, 1 << (i & 7), 99);
  };
  auto rs_one = [&](int i, int flg) {
    MMP q{}; q.A0 = Wg + (size_t)i * 256 * 512; q.B0 = Ubuf;
    q.O0a = OUTS; q.O1a = SKIP; q.Obf0 = OUTbf;
    q.si0 = STATS + (size_t)(2 + 2 * i) * SLOTW; q.invN = invN_h;
    q.Uc0 = UVu + (size_t)i * 256; q.Vc0 = UVv + (size_t)i * 256;
    q.rb0 = res_b + (size_t)i * 128; q.sb0 = sk_b + (size_t)i * 128;
    q.feat = feat; q.dupO0 = OUT2; q.dupObf = OUT2bf; q.dupO1 = SKIP2;
    q.K = 512;
    if (flg == 2)      mm6<2, 64, 2, 128><<<dim3(64, 2, B_), 256, 0, stream>>>(q);
    else if (flg == 4) mm6<2, 64, 4, 128><<<dim3(64, 2, B_), 256, 0, stream>>>(q);
    else if (flg == 8) mm6<2, 64, 8, 128><<<dim3(64, 2, B_), 256, 0, stream>>>(q);
    else               mm6<2, 64, 0, 128><<<dim3(64, 2, B_), 256, 0, stream>>>(q);
  };

  for (int i = 0; i < 16; ++i) {
    pw_one(i);
    dw_one(i);
    rs_one(i, (i == 0) ? 8 : (i == 7) ? 2 : (i == 15) ? 4 : 0);
  }

  // ---- paired blocks: branch1 = 16+j, branch2 = 24+j
  for (int j = 0; j < 8; ++j) {
    const int i1 = 16 + j, i2 = 24 + j;
    float* sA1 = STATS + (size_t)(1 + 2 * i1) * SLOTW;
    float* sB1 = STATS + (size_t)(2 + 2 * i1) * SLOTW;
    float* sA2 = STATS + (size_t)(1 + 2 * i2) * SLOTW;
    float* sB2 = STATS + (size_t)(2 + 2 * i2) * SLOTW;
    {
      MMP q{};
      q.A0 = Wpw + (size_t)i1 * 512 * 128; q.A1 = Wpw + (size_t)i2 * 512 * 128;
      q.B0 = OUTbf; q.B1 = OUT2bf;
      q.bias0 = pw_b + (size_t)i1 * 512; q.bias1 = pw_b + (size_t)i2 * 512;
      q.Obf0 = YbufD; q.Obf1 = YbufD + 4 * YSST;
      q.al0 = p1 + i1; q.al1 = p1 + i2;
      q.so0 = sA1; q.so1 = sA2; q.K = 128;
      mm6<1, 128, 1, 128><<<dim3(32, 4, 2 * B_), 256, 0, stream>>>(q);
    }
    dw3<<<dim3(250, 2 * B_), 256, 0, stream>>>(
        YbufD, Ubuf,
        dw_w + (size_t)i1 * 512 * 3, dw_w + (size_t)i2 * 512 * 3,
        dw_b + (size_t)i1 * 512, dw_b + (size_t)i2 * 512,
        n1g + (size_t)i1 * 512, n1g + (size_t)i2 * 512,
        n1b + (size_t)i1 * 512, n1b + (size_t)i2 * 512,
        p2 + i1, p2 + i2, sA1, sA2, invN_h, sB1, sB2, 1 << (j & 7), B_);
    {
      MMP q{};
      q.A0 = Wg + (size_t)i1 * 256 * 512; q.A1 = Wg + (size_t)i2 * 256 * 512;
      q.B0 = Ubuf; q.B1 = Ubuf + 4 * USST;
      q.O0a = OUTS; q.O0b = OUT2; q.O1a = SKIP; q.O1b = SKIP2;
      q.Obf0 = OUTbf; q.Obf1 = OUT2bf;
      q.si0 = sB1; q.si1 = sB2; q.invN = invN_h;
      q.Uc0 = UVu + (size_t)i1 * 256; q.Uc1 = UVu + (size_t)i2 * 256;
      q.Vc0 = UVv + (size_t)i1 * 256; q.Vc1 = UVv + (size_t)i2 * 256;
      q.rb0 = res_b + (size_t)i1 * 128; q.rb1 = res_b + (size_t)i2 * 128;
      q.sb0 = sk_b + (size_t)i1 * 128; q.sb1 = sk_b + (size_t)i2 * 128;
      q.K = 512;
      if (j == 7) {
        // final skip update: also emit heads input SKbf = f2bf(prelu(nv))
        q.al0 = h1_p; q.al1 = h2_p;
        q.skb0 = SKbf; q.skb1 = SKbf + npr;
        mm6<2, 128, 17, 128><<<dim3(32, 2, 2 * B_), 256, 0, stream>>>(q);
      } else {
        mm6<2, 128, 1, 128><<<dim3(32, 2, 2 * B_), 256, 0, stream>>>(q);
      }
    }
  }

  // ---- heads (both in one pass; SKbf written by j=7 rs epilogue)
  {
    MMP q{};
    q.A0 = Wh1; q.A1 = Wh2;
    q.B0 = SKbf; q.B1 = SKbf + npr;
    q.bias0 = h1_b; q.bias1 = h2_b;
    q.O0a = out1; q.O0b = out2; q.K = 128;
    mm6<3, 128, 1, 128><<<dim3(32, 2, 2 * B_), 256, 0, stream>>>(q);
  }
}